// Round 1
// baseline (4085.836 us; speedup 1.0000x reference)
//
#include <hip/hip_runtime.h>
#include <cstdint>
#include <cstddef>

#define LRELU(x) fmaxf((x), 0.2f*(x))

// ---------------- GEMM1: h1[N,128] = x[N,128] @ W1[128,128] ----------------
// 32 nodes/block, 256 threads, 4 nodes x 4 cols per thread, split-K LDS for W1.
__global__ __launch_bounds__(256) void k_gemm1(const float* __restrict__ x,
                                               const float* __restrict__ W1,
                                               float* __restrict__ h1, int N) {
  __shared__ float Ws[64*128];    // 32 KB (half of W1 per phase)
  __shared__ float xs[32*132];    // 16.9 KB, padded stride 132 (bank-conflict-free)
  int t = threadIdx.x;
  int n0 = blockIdx.x * 32;
  const float4* W4 = (const float4*)W1;
  const float4* x4 = (const float4*)x;
  float4* Ws4 = (float4*)Ws;
  int cg = t & 31;   // cols cg*4 .. cg*4+3
  int ng = t >> 5;   // nodes ng*4 .. ng*4+3
  float acc[4][4] = {};
  for (int p = 0; p < 2; ++p) {
    for (int i = 0; i < 8; ++i) {
      int idx = t + i*256;
      Ws4[idx] = W4[p*2048 + idx];
    }
    if (p == 0) {
      for (int i = 0; i < 4; ++i) {
        int idx = t + i*256;              // 1024 float4 = 32 rows x 32 float4
        int row = idx >> 5, c4 = idx & 31;
        int nrow = n0 + row; if (nrow >= N) nrow = N - 1;
        float4 v = x4[(size_t)nrow*32 + c4];
        float* dst = &xs[row*132 + c4*4];
        dst[0] = v.x; dst[1] = v.y; dst[2] = v.z; dst[3] = v.w;
      }
    }
    __syncthreads();
    #pragma unroll 4
    for (int k = 0; k < 64; ++k) {
      float4 wv = Ws4[k*32 + cg];
      int kk = p*64 + k;
      float xv0 = xs[(ng*4+0)*132 + kk];
      float xv1 = xs[(ng*4+1)*132 + kk];
      float xv2 = xs[(ng*4+2)*132 + kk];
      float xv3 = xs[(ng*4+3)*132 + kk];
      acc[0][0] += xv0*wv.x; acc[0][1] += xv0*wv.y; acc[0][2] += xv0*wv.z; acc[0][3] += xv0*wv.w;
      acc[1][0] += xv1*wv.x; acc[1][1] += xv1*wv.y; acc[1][2] += xv1*wv.z; acc[1][3] += xv1*wv.w;
      acc[2][0] += xv2*wv.x; acc[2][1] += xv2*wv.y; acc[2][2] += xv2*wv.z; acc[2][3] += xv2*wv.w;
      acc[3][0] += xv3*wv.x; acc[3][1] += xv3*wv.y; acc[3][2] += xv3*wv.z; acc[3][3] += xv3*wv.w;
    }
    __syncthreads();
  }
  for (int i = 0; i < 4; ++i) {
    int n = n0 + ng*4 + i;
    if (n < N) {
      float4 o = make_float4(acc[i][0], acc[i][1], acc[i][2], acc[i][3]);
      ((float4*)h1)[(size_t)n*32 + cg] = o;
    }
  }
}

// ---------------- attention scalars layer 1: a_s/a_d [N,4] ----------------
__global__ __launch_bounds__(256) void k_att1(const float* __restrict__ h1,
    const float* __restrict__ att_s, const float* __restrict__ att_d,
    float* __restrict__ a_s, float* __restrict__ a_d, int N) {
  int t = threadIdx.x;
  int n = blockIdx.x*2 + (t >> 7);
  if (n >= N) return;
  int ch = t & 127;                 // flat [head*32 + c] matches att flat layout
  float v = h1[(size_t)n*128 + ch];
  float sv = v * att_s[ch];
  float dv = v * att_d[ch];
  for (int off = 16; off > 0; off >>= 1) {
    sv += __shfl_down(sv, off, 32);
    dv += __shfl_down(dv, off, 32);
  }
  if ((ch & 31) == 0) {
    int head = ch >> 5;
    a_s[n*4 + head] = sv;
    a_d[n*4 + head] = dv;
  }
}

// ---------------- edge pass A layer 1: ex1[E,4], denom1[N,4] ----------------
__global__ __launch_bounds__(256) void k_edgeA1(const int* __restrict__ ei, int E, int Etot,
    const float* __restrict__ a_s, const float* __restrict__ a_d,
    float* __restrict__ ex1, float* __restrict__ denom1) {
  int e = blockIdx.x*256 + threadIdx.x;
  if (e >= Etot) return;
  int src, dst;
  if (e < E) { src = ei[e]; dst = ei[E + e]; } else { src = e - E; dst = src; }
  float4 s4 = ((const float4*)a_s)[src];
  float4 d4 = ((const float4*)a_d)[dst];
  float4 ex;
  ex.x = __expf(LRELU(s4.x + d4.x));
  ex.y = __expf(LRELU(s4.y + d4.y));
  ex.z = __expf(LRELU(s4.z + d4.z));
  ex.w = __expf(LRELU(s4.w + d4.w));
  ((float4*)ex1)[e] = ex;
  atomicAdd(&denom1[dst*4+0], ex.x);
  atomicAdd(&denom1[dst*4+1], ex.y);
  atomicAdd(&denom1[dst*4+2], ex.z);
  atomicAdd(&denom1[dst*4+3], ex.w);
}

// ---------------- edge pass B layer 1: out1[dst] += h1[src]*alpha ----------------
// 32 threads per edge, each handles float4 at channel lane*4 (head = lane>>3).
__global__ __launch_bounds__(256) void k_edgeB1(const int* __restrict__ ei, int E, int Etot,
    const float* __restrict__ h1, const float* __restrict__ ex1,
    const float* __restrict__ denom1, float* __restrict__ out1) {
  int tid = blockIdx.x*256 + threadIdx.x;
  int e = tid >> 5;
  if (e >= Etot) return;
  int lane = tid & 31;
  int src, dst;
  if (e < E) { src = ei[e]; dst = ei[E + e]; } else { src = e - E; dst = src; }
  int head = lane >> 3;
  float alpha = ex1[e*4 + head] / (denom1[dst*4 + head] + 1e-16f);
  float4 v = ((const float4*)h1)[(size_t)src*32 + lane];
  float* o = &out1[(size_t)dst*128 + lane*4];
  atomicAdd(o+0, v.x*alpha);
  atomicAdd(o+1, v.y*alpha);
  atomicAdd(o+2, v.z*alpha);
  atomicAdd(o+3, v.w*alpha);
}

// ---------------- GEMM2 + attention scalars layer 2 ----------------
// h2 = elu(out1 + b1); g[N,10] = h2 @ W2; a_s2/a_d2 = g . att2
__global__ __launch_bounds__(320) void k_gemm2(const float* __restrict__ out1,
    const float* __restrict__ b1, const float* __restrict__ W2,
    const float* __restrict__ atts2, const float* __restrict__ attd2,
    float* __restrict__ g, float* __restrict__ a_s2, float* __restrict__ a_d2, int N) {
  __shared__ float h2s[32*128];
  __shared__ float W2s[1280];
  __shared__ float gs[320];
  int t = threadIdx.x;
  int n0 = blockIdx.x * 32;
  for (int f = t; f < 1280; f += 320) W2s[f] = W2[f];
  for (int f = t; f < 4096; f += 320) {
    int row = f >> 7;
    int n = n0 + row;
    float v = 0.f;
    if (n < N) {
      v = out1[(size_t)n*128 + (f & 127)] + b1[f & 127];
      v = v > 0.f ? v : expm1f(v);
    }
    h2s[f] = v;
  }
  __syncthreads();
  int nl = t / 10, col = t - nl*10;    // 320 = 32 nodes x 10 cols
  float acc = 0.f;
  #pragma unroll 8
  for (int k = 0; k < 128; ++k)
    acc += h2s[nl*128 + k] * W2s[k*10 + col];
  gs[t] = acc;
  int n = n0 + nl;
  if (n < N) g[(size_t)n*10 + col] = acc;
  __syncthreads();
  if (t < 32 && n0 + t < N) {
    float as = 0.f, ad = 0.f;
    #pragma unroll
    for (int c = 0; c < 10; ++c) {
      float gv = gs[t*10 + c];
      as += gv * atts2[c];
      ad += gv * attd2[c];
    }
    a_s2[n0 + t] = as;
    a_d2[n0 + t] = ad;
  }
}

// ---------------- edge passes layer 2 ----------------
__global__ __launch_bounds__(256) void k_edgeA2(const int* __restrict__ ei, int E, int Etot,
    const float* __restrict__ a_s, const float* __restrict__ a_d,
    float* __restrict__ ex2, float* __restrict__ denom2) {
  int e = blockIdx.x*256 + threadIdx.x;
  if (e >= Etot) return;
  int src, dst;
  if (e < E) { src = ei[e]; dst = ei[E + e]; } else { src = e - E; dst = src; }
  float ex = __expf(LRELU(a_s[src] + a_d[dst]));
  ex2[e] = ex;
  atomicAdd(&denom2[dst], ex);
}

__global__ __launch_bounds__(256) void k_edgeB2(const int* __restrict__ ei, int E, int Etot,
    const float* __restrict__ g, const float* __restrict__ ex2,
    const float* __restrict__ denom2, float* __restrict__ out2) {
  int tid = blockIdx.x*256 + threadIdx.x;
  int e = tid / 10;
  if (e >= Etot) return;
  int c = tid - e*10;
  int src, dst;
  if (e < E) { src = ei[e]; dst = ei[E + e]; } else { src = e - E; dst = src; }
  float alpha = ex2[e] / (denom2[dst] + 1e-16f);
  atomicAdd(&out2[(size_t)dst*10 + c], g[(size_t)src*10 + c] * alpha);
}

// ---------------- final: elu(out2+b2), pool by graph ----------------
__global__ __launch_bounds__(256) void k_final(const float* __restrict__ out2,
    const float* __restrict__ b2, const int* __restrict__ batch,
    float* __restrict__ pooled, float* __restrict__ cnt, int N) {
  int n = blockIdx.x*256 + threadIdx.x;
  if (n >= N) return;
  int b = batch[n];
  #pragma unroll
  for (int c = 0; c < 10; ++c) {
    float o = out2[(size_t)n*10 + c] + b2[c];
    o = o > 0.f ? o : expm1f(o);
    atomicAdd(&pooled[b*10 + c], o);
  }
  atomicAdd(&cnt[b], 1.0f);
}

__global__ __launch_bounds__(128) void k_softmax(const float* __restrict__ pooled,
    const float* __restrict__ cnt, float* __restrict__ out) {
  int t = threadIdx.x;  // one graph per thread, 128 graphs
  float inv = 1.0f / fmaxf(cnt[t], 1.0f);
  float v[10], m = -1e30f;
  #pragma unroll
  for (int c = 0; c < 10; ++c) { v[c] = pooled[t*10 + c] * inv; m = fmaxf(m, v[c]); }
  float s = 0.f;
  #pragma unroll
  for (int c = 0; c < 10; ++c) s += __expf(v[c] - m);
  float ls = logf(s) + m;
  #pragma unroll
  for (int c = 0; c < 10; ++c) out[t*10 + c] = v[c] - ls;
}

extern "C" void kernel_launch(void* const* d_in, const int* in_sizes, int n_in,
                              void* d_out, int out_size, void* d_ws, size_t ws_size,
                              hipStream_t stream) {
  const float* x     = (const float*)d_in[0];
  const float* W1    = (const float*)d_in[1];
  const float* atts1 = (const float*)d_in[2];
  const float* attd1 = (const float*)d_in[3];
  const float* b1    = (const float*)d_in[4];
  const float* W2    = (const float*)d_in[5];
  const float* atts2 = (const float*)d_in[6];
  const float* attd2 = (const float*)d_in[7];
  const float* b2    = (const float*)d_in[8];
  const int*   ei    = (const int*)d_in[9];
  const int*   batch = (const int*)d_in[10];
  int N = in_sizes[10];
  int E = in_sizes[9] / 2;
  int Etot = E + N;

  float* ws = (float*)d_ws;
  size_t off = 0;
  float* h1     = ws + off; off += (size_t)N*128;
  float* a_s1   = ws + off; off += (size_t)N*4;
  float* a_d1   = ws + off; off += (size_t)N*4;
  float* denom1 = ws + off; off += (size_t)N*4;
  float* out1   = ws + off; off += (size_t)N*128;
  float* region = ws + off;
  size_t regionSize = (size_t)Etot*4;               // ex1 (layer 1)
  size_t l2need = (size_t)N*23 + (size_t)Etot;      // layer-2 buffers (aliased)
  if (l2need > regionSize) regionSize = l2need;
  off += regionSize;
  float* pooled = ws + off; off += 1280;
  float* cnt    = ws + off; off += 128;
  // layer-1 alias
  float* ex1 = region;
  // layer-2 aliases (valid once edge pass B1 is done)
  float* g      = region;
  float* a_s2   = region + (size_t)N*10;
  float* a_d2   = a_s2 + N;
  float* denom2 = a_d2 + N;
  float* out2   = denom2 + N;
  float* ex2    = out2 + (size_t)N*10;

  // zero accumulators (stream-ordered, graph-capture safe)
  hipMemsetAsync(denom1, 0, (size_t)N*4*sizeof(float), stream);
  hipMemsetAsync(out1,   0, (size_t)N*128*sizeof(float), stream);
  hipMemsetAsync(pooled, 0, (1280 + 128)*sizeof(float), stream);  // pooled + cnt

  k_gemm1<<<dim3((N + 31)/32), dim3(256), 0, stream>>>(x, W1, h1, N);
  k_att1<<<dim3((N + 1)/2), dim3(256), 0, stream>>>(h1, atts1, attd1, a_s1, a_d1, N);
  k_edgeA1<<<dim3((Etot + 255)/256), dim3(256), 0, stream>>>(ei, E, Etot, a_s1, a_d1, ex1, denom1);
  {
    long long th = (long long)Etot * 32;
    k_edgeB1<<<dim3((unsigned)((th + 255)/256)), dim3(256), 0, stream>>>(ei, E, Etot, h1, ex1, denom1, out1);
  }
  k_gemm2<<<dim3((N + 31)/32), dim3(320), 0, stream>>>(out1, b1, W2, atts2, attd2, g, a_s2, a_d2, N);
  hipMemsetAsync(denom2, 0, (size_t)N*11*sizeof(float), stream);  // denom2 + out2 contiguous
  k_edgeA2<<<dim3((Etot + 255)/256), dim3(256), 0, stream>>>(ei, E, Etot, a_s2, a_d2, ex2, denom2);
  {
    long long th = (long long)Etot * 10;
    k_edgeB2<<<dim3((unsigned)((th + 255)/256)), dim3(256), 0, stream>>>(ei, E, Etot, g, ex2, denom2, out2);
  }
  k_final<<<dim3((N + 255)/256), dim3(256), 0, stream>>>(out2, b2, batch, pooled, cnt, N);
  k_softmax<<<dim3(1), dim3(128), 0, stream>>>(pooled, cnt, (float*)d_out);
}

// Round 3
// 838.902 us; speedup vs baseline: 4.8705x; 4.8705x over previous
//
#include <hip/hip_runtime.h>
#include <cstdint>
#include <cstddef>

#define LRELU(x) fmaxf((x), 0.2f*(x))

// ---------------- GEMM1: h1[N,128] = x[N,128] @ W1[128,128] ----------------
__global__ __launch_bounds__(256) void k_gemm1(const float* __restrict__ x,
                                               const float* __restrict__ W1,
                                               float* __restrict__ h1, int N) {
  __shared__ float Ws[64*128];
  __shared__ float xs[32*132];
  int t = threadIdx.x;
  int n0 = blockIdx.x * 32;
  const float4* W4 = (const float4*)W1;
  const float4* x4 = (const float4*)x;
  float4* Ws4 = (float4*)Ws;
  int cg = t & 31;
  int ng = t >> 5;
  float acc[4][4] = {};
  for (int p = 0; p < 2; ++p) {
    for (int i = 0; i < 8; ++i) {
      int idx = t + i*256;
      Ws4[idx] = W4[p*2048 + idx];
    }
    if (p == 0) {
      for (int i = 0; i < 4; ++i) {
        int idx = t + i*256;
        int row = idx >> 5, c4 = idx & 31;
        int nrow = n0 + row; if (nrow >= N) nrow = N - 1;
        float4 v = x4[(size_t)nrow*32 + c4];
        float* dst = &xs[row*132 + c4*4];
        dst[0] = v.x; dst[1] = v.y; dst[2] = v.z; dst[3] = v.w;
      }
    }
    __syncthreads();
    #pragma unroll 4
    for (int k = 0; k < 64; ++k) {
      float4 wv = Ws4[k*32 + cg];
      int kk = p*64 + k;
      float xv0 = xs[(ng*4+0)*132 + kk];
      float xv1 = xs[(ng*4+1)*132 + kk];
      float xv2 = xs[(ng*4+2)*132 + kk];
      float xv3 = xs[(ng*4+3)*132 + kk];
      acc[0][0] += xv0*wv.x; acc[0][1] += xv0*wv.y; acc[0][2] += xv0*wv.z; acc[0][3] += xv0*wv.w;
      acc[1][0] += xv1*wv.x; acc[1][1] += xv1*wv.y; acc[1][2] += xv1*wv.z; acc[1][3] += xv1*wv.w;
      acc[2][0] += xv2*wv.x; acc[2][1] += xv2*wv.y; acc[2][2] += xv2*wv.z; acc[2][3] += xv2*wv.w;
      acc[3][0] += xv3*wv.x; acc[3][1] += xv3*wv.y; acc[3][2] += xv3*wv.z; acc[3][3] += xv3*wv.w;
    }
    __syncthreads();
  }
  for (int i = 0; i < 4; ++i) {
    int n = n0 + ng*4 + i;
    if (n < N) {
      float4 o = make_float4(acc[i][0], acc[i][1], acc[i][2], acc[i][3]);
      ((float4*)h1)[(size_t)n*32 + cg] = o;
    }
  }
}

// ---------------- attention scalars layer 1 ----------------
__global__ __launch_bounds__(256) void k_att1(const float* __restrict__ h1,
    const float* __restrict__ att_s, const float* __restrict__ att_d,
    float* __restrict__ a_s, float* __restrict__ a_d, int N) {
  int t = threadIdx.x;
  int n = blockIdx.x*2 + (t >> 7);
  if (n >= N) return;
  int ch = t & 127;
  float v = h1[(size_t)n*128 + ch];
  float sv = v * att_s[ch];
  float dv = v * att_d[ch];
  for (int off = 16; off > 0; off >>= 1) {
    sv += __shfl_down(sv, off, 32);
    dv += __shfl_down(dv, off, 32);
  }
  if ((ch & 31) == 0) {
    int head = ch >> 5;
    a_s[n*4 + head] = sv;
    a_d[n*4 + head] = dv;
  }
}

// ---------------- CSR build: histogram, scan, scatter ----------------
__global__ __launch_bounds__(256) void k_hist(const int* __restrict__ ei, int E,
                                              int* __restrict__ deg) {
  int e = blockIdx.x*256 + threadIdx.x;
  if (e < E) atomicAdd(&deg[ei[E + e]], 1);
}

__global__ __launch_bounds__(1024) void k_scan1(const int* __restrict__ deg,
    int* __restrict__ rowptr, int* __restrict__ bsums, int N) {
  __shared__ int s[1024];
  int t = threadIdx.x;
  int i = blockIdx.x*1024 + t;
  int v = (i < N) ? deg[i] + 1 : 0;   // +1 = self loop
  s[t] = v;
  __syncthreads();
  int val = v;
  for (int off = 1; off < 1024; off <<= 1) {
    int add = (t >= off) ? s[t - off] : 0;
    __syncthreads();
    val += add;
    s[t] = val;
    __syncthreads();
  }
  if (i < N) rowptr[i] = val - v;    // exclusive within block
  if (t == 1023) bsums[blockIdx.x] = val;
}

__global__ __launch_bounds__(128) void k_scan2(int* __restrict__ bsums, int nb) {
  __shared__ int s[128];
  int t = threadIdx.x;
  int v = (t < nb) ? bsums[t] : 0;
  s[t] = v;
  __syncthreads();
  int val = v;
  for (int off = 1; off < 128; off <<= 1) {
    int add = (t >= off) ? s[t - off] : 0;
    __syncthreads();
    val += add;
    s[t] = val;
    __syncthreads();
  }
  if (t < nb) bsums[t] = val - v;    // exclusive block offsets
}

__global__ __launch_bounds__(256) void k_scan3(int* __restrict__ rowptr,
    int* __restrict__ cursor, const int* __restrict__ bsums, int N, int Etot) {
  int i = blockIdx.x*256 + threadIdx.x;
  if (i < N) {
    int r = rowptr[i] + bsums[i >> 10];
    rowptr[i] = r;
    cursor[i] = r;
  }
  if (i == 0) rowptr[N] = Etot;
}

__global__ __launch_bounds__(256) void k_scatter(const int* __restrict__ ei, int E, int Etot,
    int* __restrict__ cursor, int* __restrict__ srcs) {
  int e = blockIdx.x*256 + threadIdx.x;
  if (e >= Etot) return;
  int src, dst;
  if (e < E) { src = ei[e]; dst = ei[E + e]; } else { src = e - E; dst = src; }
  int pos = atomicAdd(&cursor[dst], 1);
  srcs[pos] = src;
}

// ---------------- layer-1 aggregation: one wave per dst, no atomics ----------------
__global__ __launch_bounds__(256) void k_agg1(const int* __restrict__ rowptr,
    const int* __restrict__ srcs, const float* __restrict__ a_s,
    const float* __restrict__ a_d, const float* __restrict__ h1,
    float* __restrict__ out1, int N) {
  int dst = (blockIdx.x*256 + threadIdx.x) >> 6;   // one wave64 per dst
  if (dst >= N) return;
  int lane = threadIdx.x & 63;
  int beg = rowptr[dst], end = rowptr[dst+1];
  int head = lane >> 4;                             // ch = lane*2; head = ch>>5
  float ad = a_d[dst*4 + head];
  float denom = 0.f;
  for (int j = beg; j < end; ++j) {
    int s = srcs[j];
    denom += __expf(LRELU(a_s[s*4 + head] + ad));
  }
  float inv = 1.0f / (denom + 1e-16f);
  float2 acc = make_float2(0.f, 0.f);
  for (int j = beg; j < end; ++j) {
    int s = srcs[j];
    float alpha = __expf(LRELU(a_s[s*4 + head] + ad)) * inv;
    float2 v = ((const float2*)h1)[(size_t)s*64 + lane];
    acc.x += v.x * alpha;
    acc.y += v.y * alpha;
  }
  ((float2*)out1)[(size_t)dst*64 + lane] = acc;
}

// ---------------- GEMM2 + attention scalars layer 2 ----------------
__global__ __launch_bounds__(320) void k_gemm2(const float* __restrict__ out1,
    const float* __restrict__ b1, const float* __restrict__ W2,
    const float* __restrict__ atts2, const float* __restrict__ attd2,
    float* __restrict__ g, float* __restrict__ a_s2, float* __restrict__ a_d2, int N) {
  __shared__ float h2s[32*128];
  __shared__ float W2s[1280];
  __shared__ float gs[320];
  int t = threadIdx.x;
  int n0 = blockIdx.x * 32;
  for (int f = t; f < 1280; f += 320) W2s[f] = W2[f];
  for (int f = t; f < 4096; f += 320) {
    int row = f >> 7;
    int n = n0 + row;
    float v = 0.f;
    if (n < N) {
      v = out1[(size_t)n*128 + (f & 127)] + b1[f & 127];
      v = v > 0.f ? v : expm1f(v);
    }
    h2s[f] = v;
  }
  __syncthreads();
  int nl = t / 10, col = t - nl*10;
  float acc = 0.f;
  #pragma unroll 8
  for (int k = 0; k < 128; ++k)
    acc += h2s[nl*128 + k] * W2s[k*10 + col];
  gs[t] = acc;
  int n = n0 + nl;
  if (n < N) g[(size_t)n*10 + col] = acc;
  __syncthreads();
  if (t < 32 && n0 + t < N) {
    float as = 0.f, ad = 0.f;
    #pragma unroll
    for (int c = 0; c < 10; ++c) {
      float gv = gs[t*10 + c];
      as += gv * atts2[c];
      ad += gv * attd2[c];
    }
    a_s2[n0 + t] = as;
    a_d2[n0 + t] = ad;
  }
}

// ---------------- layer-2 aggregation: 16 threads per dst ----------------
__global__ __launch_bounds__(256) void k_agg2(const int* __restrict__ rowptr,
    const int* __restrict__ srcs, const float* __restrict__ a_s,
    const float* __restrict__ a_d, const float* __restrict__ g,
    float* __restrict__ out2, int N) {
  int dst = (blockIdx.x*256 + threadIdx.x) >> 4;
  if (dst >= N) return;
  int l = threadIdx.x & 15;
  int beg = rowptr[dst], end = rowptr[dst+1];
  float ad = a_d[dst];
  float denom = 0.f;
  for (int j = beg; j < end; ++j) {
    int s = srcs[j];
    denom += __expf(LRELU(a_s[s] + ad));
  }
  float inv = 1.0f / (denom + 1e-16f);
  float acc = 0.f;
  for (int j = beg; j < end; ++j) {
    int s = srcs[j];
    float alpha = __expf(LRELU(a_s[s] + ad)) * inv;
    if (l < 10) acc += g[(size_t)s*10 + l] * alpha;
  }
  if (l < 10) out2[(size_t)dst*10 + l] = acc;
}

// ---------------- final: elu(out2+b2), pool by graph (LDS-reduced) ----------------
__global__ __launch_bounds__(256) void k_final(const float* __restrict__ out2,
    const float* __restrict__ b2, const int* __restrict__ batch,
    float* __restrict__ pooled, float* __restrict__ cnt, int N) {
  __shared__ float lp[8*10];
  __shared__ float lc[8];
  __shared__ int b0s;
  int t = threadIdx.x;
  int n = blockIdx.x*256 + t;
  if (t < 80) lp[t] = 0.f;
  if (t < 8) lc[t] = 0.f;
  if (t == 0) {
    int i0 = (int)blockIdx.x * 256;
    if (i0 > N - 1) i0 = N - 1;
    b0s = batch[i0];
  }
  __syncthreads();
  int b0 = b0s;
  if (n < N) {
    int b = batch[n];
    int bl = b - b0;
    if (bl < 8) {
      #pragma unroll
      for (int c = 0; c < 10; ++c) {
        float o = out2[(size_t)n*10 + c] + b2[c];
        o = o > 0.f ? o : expm1f(o);
        atomicAdd(&lp[bl*10 + c], o);
      }
      atomicAdd(&lc[bl], 1.0f);
    } else {
      #pragma unroll
      for (int c = 0; c < 10; ++c) {
        float o = out2[(size_t)n*10 + c] + b2[c];
        o = o > 0.f ? o : expm1f(o);
        atomicAdd(&pooled[b*10 + c], o);
      }
      atomicAdd(&cnt[b], 1.0f);
    }
  }
  __syncthreads();
  if (t < 80) {
    int bl = t / 10, c = t - bl*10;
    int b = b0 + bl;
    if (b < 128 && lp[t] != 0.f) atomicAdd(&pooled[b*10 + c], lp[t]);
  }
  if (t < 8) {
    int b = b0 + t;
    if (b < 128 && lc[t] != 0.f) atomicAdd(&cnt[b], lc[t]);
  }
}

__global__ __launch_bounds__(128) void k_softmax(const float* __restrict__ pooled,
    const float* __restrict__ cnt, float* __restrict__ out) {
  int t = threadIdx.x;
  float inv = 1.0f / fmaxf(cnt[t], 1.0f);
  float v[10], m = -1e30f;
  #pragma unroll
  for (int c = 0; c < 10; ++c) { v[c] = pooled[t*10 + c] * inv; m = fmaxf(m, v[c]); }
  float s = 0.f;
  #pragma unroll
  for (int c = 0; c < 10; ++c) s += __expf(v[c] - m);
  float ls = logf(s) + m;
  #pragma unroll
  for (int c = 0; c < 10; ++c) out[t*10 + c] = v[c] - ls;
}

extern "C" void kernel_launch(void* const* d_in, const int* in_sizes, int n_in,
                              void* d_out, int out_size, void* d_ws, size_t ws_size,
                              hipStream_t stream) {
  const float* x     = (const float*)d_in[0];
  const float* W1    = (const float*)d_in[1];
  const float* atts1 = (const float*)d_in[2];
  const float* attd1 = (const float*)d_in[3];
  const float* b1    = (const float*)d_in[4];
  const float* W2    = (const float*)d_in[5];
  const float* atts2 = (const float*)d_in[6];
  const float* attd2 = (const float*)d_in[7];
  const float* b2    = (const float*)d_in[8];
  const int*   ei    = (const int*)d_in[9];
  const int*   batch = (const int*)d_in[10];
  int N = in_sizes[10];
  int E = in_sizes[9] / 2;
  int Etot = E + N;

  char* base = (char*)d_ws;
  size_t off = 0;
  auto allocF = [&](size_t n) { float* p = (float*)(base + off); off += n*sizeof(float); return p; };
  auto allocI = [&](size_t n) { int* p = (int*)(base + off); off += n*sizeof(int); return p; };

  float* h1     = allocF((size_t)N*128);
  float* out1   = allocF((size_t)N*128);
  float* a_s1   = allocF((size_t)N*4);
  float* a_d1   = allocF((size_t)N*4);
  float* g      = allocF((size_t)N*10);
  float* a_s2   = allocF(N);
  float* a_d2   = allocF(N);
  float* out2   = allocF((size_t)N*10);
  float* pooled = allocF(1280);
  float* cnt    = allocF(128);
  int* deg    = allocI(N);
  int* rowptr = allocI(N + 1);
  int* cursor = allocI(N);
  int* bsums  = allocI(128);
  int* srcs   = allocI(Etot);

  int nScanBlocks = (N + 1023) / 1024;

  (void)hipMemsetAsync(deg, 0, (size_t)N*sizeof(int), stream);
  (void)hipMemsetAsync(pooled, 0, (1280 + 128)*sizeof(float), stream);

  // CSR build
  k_hist<<<dim3((E + 255)/256), dim3(256), 0, stream>>>(ei, E, deg);
  k_scan1<<<dim3(nScanBlocks), dim3(1024), 0, stream>>>(deg, rowptr, bsums, N);
  k_scan2<<<dim3(1), dim3(128), 0, stream>>>(bsums, nScanBlocks);
  k_scan3<<<dim3((N + 255)/256), dim3(256), 0, stream>>>(rowptr, cursor, bsums, N, Etot);
  k_scatter<<<dim3((Etot + 255)/256), dim3(256), 0, stream>>>(ei, E, Etot, cursor, srcs);

  k_gemm1<<<dim3((N + 31)/32), dim3(256), 0, stream>>>(x, W1, h1, N);
  k_att1<<<dim3((N + 1)/2), dim3(256), 0, stream>>>(h1, atts1, attd1, a_s1, a_d1, N);
  k_agg1<<<dim3((N*64 + 255)/256), dim3(256), 0, stream>>>(rowptr, srcs, a_s1, a_d1, h1, out1, N);

  k_gemm2<<<dim3((N + 31)/32), dim3(320), 0, stream>>>(out1, b1, W2, atts2, attd2, g, a_s2, a_d2, N);
  k_agg2<<<dim3((N*16 + 255)/256), dim3(256), 0, stream>>>(rowptr, srcs, a_s2, a_d2, g, out2, N);

  k_final<<<dim3((N + 255)/256), dim3(256), 0, stream>>>(out2, b2, batch, pooled, cnt, N);
  k_softmax<<<dim3(1), dim3(128), 0, stream>>>(pooled, cnt, (float*)d_out);
}

// Round 4
// 578.956 us; speedup vs baseline: 7.0573x; 1.4490x over previous
//
#include <hip/hip_runtime.h>
#include <cstdint>
#include <cstddef>

#define LRELU(x) fmaxf((x), 0.2f*(x))

// ------- GEMM1: h1[N,128] = x[N,128] @ W1[128,128], fused a_s1/a_d1 epilogue -------
__global__ __launch_bounds__(256) void k_gemm1(const float* __restrict__ x,
                                               const float* __restrict__ W1,
                                               const float* __restrict__ atts1,
                                               const float* __restrict__ attd1,
                                               float* __restrict__ h1,
                                               float* __restrict__ a_s, float* __restrict__ a_d,
                                               int N) {
  __shared__ float Ws[64*128];
  __shared__ float xs[32*132];
  int t = threadIdx.x;
  int n0 = blockIdx.x * 32;
  const float4* W4 = (const float4*)W1;
  const float4* x4 = (const float4*)x;
  float4* Ws4 = (float4*)Ws;
  int cg = t & 31;
  int ng = t >> 5;
  float acc[4][4] = {};
  for (int p = 0; p < 2; ++p) {
    for (int i = 0; i < 8; ++i) {
      int idx = t + i*256;
      Ws4[idx] = W4[p*2048 + idx];
    }
    if (p == 0) {
      for (int i = 0; i < 4; ++i) {
        int idx = t + i*256;
        int row = idx >> 5, c4 = idx & 31;
        int nrow = n0 + row; if (nrow >= N) nrow = N - 1;
        float4 v = x4[(size_t)nrow*32 + c4];
        float* dst = &xs[row*132 + c4*4];
        dst[0] = v.x; dst[1] = v.y; dst[2] = v.z; dst[3] = v.w;
      }
    }
    __syncthreads();
    #pragma unroll 4
    for (int k = 0; k < 64; ++k) {
      float4 wv = Ws4[k*32 + cg];
      int kk = p*64 + k;
      float xv0 = xs[(ng*4+0)*132 + kk];
      float xv1 = xs[(ng*4+1)*132 + kk];
      float xv2 = xs[(ng*4+2)*132 + kk];
      float xv3 = xs[(ng*4+3)*132 + kk];
      acc[0][0] += xv0*wv.x; acc[0][1] += xv0*wv.y; acc[0][2] += xv0*wv.z; acc[0][3] += xv0*wv.w;
      acc[1][0] += xv1*wv.x; acc[1][1] += xv1*wv.y; acc[1][2] += xv1*wv.z; acc[1][3] += xv1*wv.w;
      acc[2][0] += xv2*wv.x; acc[2][1] += xv2*wv.y; acc[2][2] += xv2*wv.z; acc[2][3] += xv2*wv.w;
      acc[3][0] += xv3*wv.x; acc[3][1] += xv3*wv.y; acc[3][2] += xv3*wv.z; acc[3][3] += xv3*wv.w;
    }
    __syncthreads();
  }
  float4 as4 = ((const float4*)atts1)[cg];
  float4 ad4 = ((const float4*)attd1)[cg];
  int head = cg >> 3;
  #pragma unroll
  for (int i = 0; i < 4; ++i) {
    int n = n0 + ng*4 + i;
    if (n < N) {
      float4 o = make_float4(acc[i][0], acc[i][1], acc[i][2], acc[i][3]);
      ((float4*)h1)[(size_t)n*32 + cg] = o;
      float ps = o.x*as4.x + o.y*as4.y + o.z*as4.z + o.w*as4.w;
      float pd = o.x*ad4.x + o.y*ad4.y + o.z*ad4.z + o.w*ad4.w;
      // reduce over the 8 lanes of this head (cg within head group)
      #pragma unroll
      for (int off = 4; off > 0; off >>= 1) {
        ps += __shfl_xor(ps, off, 8);
        pd += __shfl_xor(pd, off, 8);
      }
      if ((cg & 7) == 0) {
        a_s[n*4 + head] = ps;
        a_d[n*4 + head] = pd;
      }
    }
  }
}

// ---------------- CSR build: histogram, scan, scatter ----------------
__global__ __launch_bounds__(256) void k_hist(const int* __restrict__ ei, int E,
                                              int* __restrict__ deg) {
  int e = blockIdx.x*256 + threadIdx.x;
  if (e < E) atomicAdd(&deg[ei[E + e]], 1);
}

__global__ __launch_bounds__(1024) void k_scan1(const int* __restrict__ deg,
    int* __restrict__ rowptr, int* __restrict__ bsums, int N) {
  __shared__ int s[1024];
  int t = threadIdx.x;
  int i = blockIdx.x*1024 + t;
  int v = (i < N) ? deg[i] + 1 : 0;   // +1 = self loop
  s[t] = v;
  __syncthreads();
  int val = v;
  for (int off = 1; off < 1024; off <<= 1) {
    int add = (t >= off) ? s[t - off] : 0;
    __syncthreads();
    val += add;
    s[t] = val;
    __syncthreads();
  }
  if (i < N) rowptr[i] = val - v;
  if (t == 1023) bsums[blockIdx.x] = val;
}

__global__ __launch_bounds__(128) void k_scan2(int* __restrict__ bsums, int nb) {
  __shared__ int s[128];
  int t = threadIdx.x;
  int v = (t < nb) ? bsums[t] : 0;
  s[t] = v;
  __syncthreads();
  int val = v;
  for (int off = 1; off < 128; off <<= 1) {
    int add = (t >= off) ? s[t - off] : 0;
    __syncthreads();
    val += add;
    s[t] = val;
    __syncthreads();
  }
  if (t < nb) bsums[t] = val - v;
}

__global__ __launch_bounds__(256) void k_scan3(int* __restrict__ rowptr,
    int* __restrict__ cursor, const int* __restrict__ bsums, int N, int Etot) {
  int i = blockIdx.x*256 + threadIdx.x;
  if (i < N) {
    int r = rowptr[i] + bsums[i >> 10];
    rowptr[i] = r;
    cursor[i] = r;
  }
  if (i == 0) rowptr[N] = Etot;
}

__global__ __launch_bounds__(256) void k_scatter(const int* __restrict__ ei, int E, int Etot,
    int* __restrict__ cursor, int* __restrict__ srcs) {
  int e = blockIdx.x*256 + threadIdx.x;
  if (e >= Etot) return;
  int src, dst;
  if (e < E) { src = ei[e]; dst = ei[E + e]; } else { src = e - E; dst = src; }
  int pos = atomicAdd(&cursor[dst], 1);
  srcs[pos] = src;
}

// -------- layer-1 aggregation: 32 lanes/dst, single-pass softmax, 4x unroll --------
__global__ __launch_bounds__(256) void k_agg1(const int* __restrict__ rowptr,
    const int* __restrict__ srcs, const float* __restrict__ a_s,
    const float* __restrict__ a_d, const float* __restrict__ h1,
    float* __restrict__ out1, int N) {
  int dst = (blockIdx.x*256 + threadIdx.x) >> 5;   // 32 lanes per dst
  if (dst >= N) return;
  int l = threadIdx.x & 31;
  int beg = rowptr[dst], end = rowptr[dst+1];
  int head = l >> 3;
  float ad = a_d[dst*4 + head];
  const float4* h4 = (const float4*)h1;
  float denom = 0.f;
  float4 acc = make_float4(0.f, 0.f, 0.f, 0.f);
  int j = beg;
  for (; j + 4 <= end; j += 4) {
    int s0 = srcs[j], s1 = srcs[j+1], s2 = srcs[j+2], s3 = srcs[j+3];
    float w0 = __expf(LRELU(a_s[s0*4 + head] + ad));
    float w1 = __expf(LRELU(a_s[s1*4 + head] + ad));
    float w2 = __expf(LRELU(a_s[s2*4 + head] + ad));
    float w3 = __expf(LRELU(a_s[s3*4 + head] + ad));
    float4 v0 = h4[(size_t)s0*32 + l];
    float4 v1 = h4[(size_t)s1*32 + l];
    float4 v2 = h4[(size_t)s2*32 + l];
    float4 v3 = h4[(size_t)s3*32 + l];
    denom += (w0 + w1) + (w2 + w3);
    acc.x += w0*v0.x + w1*v1.x + w2*v2.x + w3*v3.x;
    acc.y += w0*v0.y + w1*v1.y + w2*v2.y + w3*v3.y;
    acc.z += w0*v0.z + w1*v1.z + w2*v2.z + w3*v3.z;
    acc.w += w0*v0.w + w1*v1.w + w2*v2.w + w3*v3.w;
  }
  for (; j < end; ++j) {
    int s = srcs[j];
    float w = __expf(LRELU(a_s[s*4 + head] + ad));
    float4 v = h4[(size_t)s*32 + l];
    denom += w;
    acc.x += w*v.x; acc.y += w*v.y; acc.z += w*v.z; acc.w += w*v.w;
  }
  float inv = 1.0f / (denom + 1e-16f);
  ((float4*)out1)[(size_t)dst*32 + l] =
      make_float4(acc.x*inv, acc.y*inv, acc.z*inv, acc.w*inv);
}

// ---------------- GEMM2 + attention scalars layer 2 ----------------
__global__ __launch_bounds__(320) void k_gemm2(const float* __restrict__ out1,
    const float* __restrict__ b1, const float* __restrict__ W2,
    const float* __restrict__ atts2, const float* __restrict__ attd2,
    float* __restrict__ g, float* __restrict__ a_s2, float* __restrict__ a_d2, int N) {
  __shared__ float h2s[32*128];
  __shared__ float W2s[1280];
  __shared__ float gs[320];
  int t = threadIdx.x;
  int n0 = blockIdx.x * 32;
  for (int f = t; f < 1280; f += 320) W2s[f] = W2[f];
  for (int f = t; f < 4096; f += 320) {
    int row = f >> 7;
    int n = n0 + row;
    float v = 0.f;
    if (n < N) {
      v = out1[(size_t)n*128 + (f & 127)] + b1[f & 127];
      v = v > 0.f ? v : expm1f(v);
    }
    h2s[f] = v;
  }
  __syncthreads();
  int nl = t / 10, col = t - nl*10;
  float acc = 0.f;
  #pragma unroll 8
  for (int k = 0; k < 128; ++k)
    acc += h2s[nl*128 + k] * W2s[k*10 + col];
  gs[t] = acc;
  int n = n0 + nl;
  if (n < N) g[(size_t)n*10 + col] = acc;
  __syncthreads();
  if (t < 32 && n0 + t < N) {
    float as = 0.f, ad = 0.f;
    #pragma unroll
    for (int c = 0; c < 10; ++c) {
      float gv = gs[t*10 + c];
      as += gv * atts2[c];
      ad += gv * attd2[c];
    }
    a_s2[n0 + t] = as;
    a_d2[n0 + t] = ad;
  }
}

// -------- layer-2 aggregation: 16 lanes/dst, single-pass softmax, 4x unroll --------
__global__ __launch_bounds__(256) void k_agg2(const int* __restrict__ rowptr,
    const int* __restrict__ srcs, const float* __restrict__ a_s,
    const float* __restrict__ a_d, const float* __restrict__ g,
    float* __restrict__ out2, int N) {
  int dst = (blockIdx.x*256 + threadIdx.x) >> 4;
  if (dst >= N) return;
  int l = threadIdx.x & 15;
  int beg = rowptr[dst], end = rowptr[dst+1];
  float ad = a_d[dst];
  float denom = 0.f;
  float acc = 0.f;
  bool act = (l < 10);
  int li = act ? l : 0;
  int j = beg;
  for (; j + 4 <= end; j += 4) {
    int s0 = srcs[j], s1 = srcs[j+1], s2 = srcs[j+2], s3 = srcs[j+3];
    float w0 = __expf(LRELU(a_s[s0] + ad));
    float w1 = __expf(LRELU(a_s[s1] + ad));
    float w2 = __expf(LRELU(a_s[s2] + ad));
    float w3 = __expf(LRELU(a_s[s3] + ad));
    float g0 = g[(size_t)s0*10 + li];
    float g1 = g[(size_t)s1*10 + li];
    float g2 = g[(size_t)s2*10 + li];
    float g3 = g[(size_t)s3*10 + li];
    denom += (w0 + w1) + (w2 + w3);
    acc += w0*g0 + w1*g1 + w2*g2 + w3*g3;
  }
  for (; j < end; ++j) {
    int s = srcs[j];
    float w = __expf(LRELU(a_s[s] + ad));
    float gv = g[(size_t)s*10 + li];
    denom += w;
    acc += w*gv;
  }
  if (act) out2[(size_t)dst*10 + l] = acc / (denom + 1e-16f);
}

// ---------------- final: elu(out2+b2), pool by graph (LDS-reduced) ----------------
__global__ __launch_bounds__(256) void k_final(const float* __restrict__ out2,
    const float* __restrict__ b2, const int* __restrict__ batch,
    float* __restrict__ pooled, float* __restrict__ cnt, int N) {
  __shared__ float lp[8*10];
  __shared__ float lc[8];
  __shared__ int b0s;
  int t = threadIdx.x;
  int n = blockIdx.x*256 + t;
  if (t < 80) lp[t] = 0.f;
  if (t < 8) lc[t] = 0.f;
  if (t == 0) {
    int i0 = (int)blockIdx.x * 256;
    if (i0 > N - 1) i0 = N - 1;
    b0s = batch[i0];
  }
  __syncthreads();
  int b0 = b0s;
  if (n < N) {
    int b = batch[n];
    int bl = b - b0;
    if (bl < 8) {
      #pragma unroll
      for (int c = 0; c < 10; ++c) {
        float o = out2[(size_t)n*10 + c] + b2[c];
        o = o > 0.f ? o : expm1f(o);
        atomicAdd(&lp[bl*10 + c], o);
      }
      atomicAdd(&lc[bl], 1.0f);
    } else {
      #pragma unroll
      for (int c = 0; c < 10; ++c) {
        float o = out2[(size_t)n*10 + c] + b2[c];
        o = o > 0.f ? o : expm1f(o);
        atomicAdd(&pooled[b*10 + c], o);
      }
      atomicAdd(&cnt[b], 1.0f);
    }
  }
  __syncthreads();
  if (t < 80) {
    int bl = t / 10, c = t - bl*10;
    int b = b0 + bl;
    if (b < 128 && lp[t] != 0.f) atomicAdd(&pooled[b*10 + c], lp[t]);
  }
  if (t < 8) {
    int b = b0 + t;
    if (b < 128 && lc[t] != 0.f) atomicAdd(&cnt[b], lc[t]);
  }
}

__global__ __launch_bounds__(128) void k_softmax(const float* __restrict__ pooled,
    const float* __restrict__ cnt, float* __restrict__ out) {
  int t = threadIdx.x;
  float inv = 1.0f / fmaxf(cnt[t], 1.0f);
  float v[10], m = -1e30f;
  #pragma unroll
  for (int c = 0; c < 10; ++c) { v[c] = pooled[t*10 + c] * inv; m = fmaxf(m, v[c]); }
  float s = 0.f;
  #pragma unroll
  for (int c = 0; c < 10; ++c) s += __expf(v[c] - m);
  float ls = logf(s) + m;
  #pragma unroll
  for (int c = 0; c < 10; ++c) out[t*10 + c] = v[c] - ls;
}

extern "C" void kernel_launch(void* const* d_in, const int* in_sizes, int n_in,
                              void* d_out, int out_size, void* d_ws, size_t ws_size,
                              hipStream_t stream) {
  const float* x     = (const float*)d_in[0];
  const float* W1    = (const float*)d_in[1];
  const float* atts1 = (const float*)d_in[2];
  const float* attd1 = (const float*)d_in[3];
  const float* b1    = (const float*)d_in[4];
  const float* W2    = (const float*)d_in[5];
  const float* atts2 = (const float*)d_in[6];
  const float* attd2 = (const float*)d_in[7];
  const float* b2    = (const float*)d_in[8];
  const int*   ei    = (const int*)d_in[9];
  const int*   batch = (const int*)d_in[10];
  int N = in_sizes[10];
  int E = in_sizes[9] / 2;
  int Etot = E + N;

  char* base = (char*)d_ws;
  size_t off = 0;
  auto allocF = [&](size_t n) { float* p = (float*)(base + off); off += n*sizeof(float); return p; };
  auto allocI = [&](size_t n) { int* p = (int*)(base + off); off += n*sizeof(int); return p; };

  float* h1     = allocF((size_t)N*128);
  float* out1   = allocF((size_t)N*128);
  float* a_s1   = allocF((size_t)N*4);
  float* a_d1   = allocF((size_t)N*4);
  float* g      = allocF((size_t)N*10);
  float* a_s2   = allocF(N);
  float* a_d2   = allocF(N);
  float* out2   = allocF((size_t)N*10);
  float* pooled = allocF(1280);
  float* cnt    = allocF(128);
  int* deg    = allocI(N);
  int* rowptr = allocI(N + 1);
  int* cursor = allocI(N);
  int* bsums  = allocI(128);
  int* srcs   = allocI(Etot);

  int nScanBlocks = (N + 1023) / 1024;

  (void)hipMemsetAsync(deg, 0, (size_t)N*sizeof(int), stream);
  (void)hipMemsetAsync(pooled, 0, (1280 + 128)*sizeof(float), stream);

  // CSR build
  k_hist<<<dim3((E + 255)/256), dim3(256), 0, stream>>>(ei, E, deg);
  k_scan1<<<dim3(nScanBlocks), dim3(1024), 0, stream>>>(deg, rowptr, bsums, N);
  k_scan2<<<dim3(1), dim3(128), 0, stream>>>(bsums, nScanBlocks);
  k_scan3<<<dim3((N + 255)/256), dim3(256), 0, stream>>>(rowptr, cursor, bsums, N, Etot);
  k_scatter<<<dim3((Etot + 255)/256), dim3(256), 0, stream>>>(ei, E, Etot, cursor, srcs);

  k_gemm1<<<dim3((N + 31)/32), dim3(256), 0, stream>>>(x, W1, atts1, attd1, h1, a_s1, a_d1, N);
  k_agg1<<<dim3((N*32 + 255)/256), dim3(256), 0, stream>>>(rowptr, srcs, a_s1, a_d1, h1, out1, N);

  k_gemm2<<<dim3((N + 31)/32), dim3(320), 0, stream>>>(out1, b1, W2, atts2, attd2, g, a_s2, a_d2, N);
  k_agg2<<<dim3((N*16 + 255)/256), dim3(256), 0, stream>>>(rowptr, srcs, a_s2, a_d2, g, out2, N);

  k_final<<<dim3((N + 255)/256), dim3(256), 0, stream>>>(out2, b2, batch, pooled, cnt, N);
  k_softmax<<<dim3(1), dim3(128), 0, stream>>>(pooled, cnt, (float*)d_out);
}

// Round 5
// 510.988 us; speedup vs baseline: 7.9960x; 1.1330x over previous
//
#include <hip/hip_runtime.h>
#include <cstdint>
#include <cstddef>

#define LRELU(x) fmaxf((x), 0.2f*(x))

__device__ inline unsigned short f2bf(float f) {
  unsigned u = __float_as_uint(f);
  u += 0x8000u;                      // round-half-up to nearest bf16
  return (unsigned short)(u >> 16);
}
__device__ inline float bf2f(unsigned short s) {
  return __uint_as_float((unsigned)s << 16);
}

// ------- GEMM1: h1b[N,128](bf16) = x @ W1, fused f32 a_s1/a_d1 epilogue -------
__global__ __launch_bounds__(256) void k_gemm1(const float* __restrict__ x,
                                               const float* __restrict__ W1,
                                               const float* __restrict__ atts1,
                                               const float* __restrict__ attd1,
                                               unsigned short* __restrict__ h1b,
                                               float* __restrict__ a_s, float* __restrict__ a_d,
                                               int N) {
  __shared__ float Ws[64*128];
  __shared__ float xs[32*132];
  int t = threadIdx.x;
  int n0 = blockIdx.x * 32;
  const float4* W4 = (const float4*)W1;
  const float4* x4 = (const float4*)x;
  float4* Ws4 = (float4*)Ws;
  int cg = t & 31;
  int ng = t >> 5;
  float acc[4][4] = {};
  for (int p = 0; p < 2; ++p) {
    for (int i = 0; i < 8; ++i) {
      int idx = t + i*256;
      Ws4[idx] = W4[p*2048 + idx];
    }
    if (p == 0) {
      for (int i = 0; i < 4; ++i) {
        int idx = t + i*256;
        int row = idx >> 5, c4 = idx & 31;
        int nrow = n0 + row; if (nrow >= N) nrow = N - 1;
        float4 v = x4[(size_t)nrow*32 + c4];
        float* dst = &xs[row*132 + c4*4];
        dst[0] = v.x; dst[1] = v.y; dst[2] = v.z; dst[3] = v.w;
      }
    }
    __syncthreads();
    #pragma unroll 4
    for (int k = 0; k < 64; ++k) {
      float4 wv = Ws4[k*32 + cg];
      int kk = p*64 + k;
      float xv0 = xs[(ng*4+0)*132 + kk];
      float xv1 = xs[(ng*4+1)*132 + kk];
      float xv2 = xs[(ng*4+2)*132 + kk];
      float xv3 = xs[(ng*4+3)*132 + kk];
      acc[0][0] += xv0*wv.x; acc[0][1] += xv0*wv.y; acc[0][2] += xv0*wv.z; acc[0][3] += xv0*wv.w;
      acc[1][0] += xv1*wv.x; acc[1][1] += xv1*wv.y; acc[1][2] += xv1*wv.z; acc[1][3] += xv1*wv.w;
      acc[2][0] += xv2*wv.x; acc[2][1] += xv2*wv.y; acc[2][2] += xv2*wv.z; acc[2][3] += xv2*wv.w;
      acc[3][0] += xv3*wv.x; acc[3][1] += xv3*wv.y; acc[3][2] += xv3*wv.z; acc[3][3] += xv3*wv.w;
    }
    __syncthreads();
  }
  float4 as4 = ((const float4*)atts1)[cg];
  float4 ad4 = ((const float4*)attd1)[cg];
  int head = cg >> 3;
  #pragma unroll
  for (int i = 0; i < 4; ++i) {
    int n = n0 + ng*4 + i;
    if (n < N) {
      float4 o = make_float4(acc[i][0], acc[i][1], acc[i][2], acc[i][3]);
      ushort4 hb;
      hb.x = f2bf(o.x); hb.y = f2bf(o.y); hb.z = f2bf(o.z); hb.w = f2bf(o.w);
      ((ushort4*)h1b)[(size_t)n*32 + cg] = hb;
      float ps = o.x*as4.x + o.y*as4.y + o.z*as4.z + o.w*as4.w;
      float pd = o.x*ad4.x + o.y*ad4.y + o.z*ad4.z + o.w*ad4.w;
      #pragma unroll
      for (int off = 4; off > 0; off >>= 1) {
        ps += __shfl_xor(ps, off, 8);
        pd += __shfl_xor(pd, off, 8);
      }
      if ((cg & 7) == 0) {
        a_s[n*4 + head] = ps;
        a_d[n*4 + head] = pd;
      }
    }
  }
}

// ---------------- CSR build: histogram, scan, scatter ----------------
__global__ __launch_bounds__(256) void k_hist(const int* __restrict__ ei, int E,
                                              int* __restrict__ deg) {
  int e = blockIdx.x*256 + threadIdx.x;
  if (e < E) atomicAdd(&deg[ei[E + e]], 1);
}

__global__ __launch_bounds__(1024) void k_scan1(const int* __restrict__ deg,
    int* __restrict__ rowptr, int* __restrict__ bsums, int N) {
  __shared__ int s[1024];
  int t = threadIdx.x;
  int i = blockIdx.x*1024 + t;
  int v = (i < N) ? deg[i] + 1 : 0;   // +1 = self loop
  s[t] = v;
  __syncthreads();
  int val = v;
  for (int off = 1; off < 1024; off <<= 1) {
    int add = (t >= off) ? s[t - off] : 0;
    __syncthreads();
    val += add;
    s[t] = val;
    __syncthreads();
  }
  if (i < N) rowptr[i] = val - v;
  if (t == 1023) bsums[blockIdx.x] = val;
}

__global__ __launch_bounds__(128) void k_scan2(int* __restrict__ bsums, int nb) {
  __shared__ int s[128];
  int t = threadIdx.x;
  int v = (t < nb) ? bsums[t] : 0;
  s[t] = v;
  __syncthreads();
  int val = v;
  for (int off = 1; off < 128; off <<= 1) {
    int add = (t >= off) ? s[t - off] : 0;
    __syncthreads();
    val += add;
    s[t] = val;
    __syncthreads();
  }
  if (t < nb) bsums[t] = val - v;
}

__global__ __launch_bounds__(256) void k_scan3(int* __restrict__ rowptr,
    int* __restrict__ cursor, const int* __restrict__ bsums, int N, int Etot) {
  int i = blockIdx.x*256 + threadIdx.x;
  if (i < N) {
    int r = rowptr[i] + bsums[i >> 10];
    rowptr[i] = r;
    cursor[i] = r;
  }
  if (i == 0) rowptr[N] = Etot;
}

__global__ __launch_bounds__(256) void k_scatter(const int* __restrict__ ei, int E, int Etot,
    int* __restrict__ cursor, int* __restrict__ srcs) {
  int e = blockIdx.x*256 + threadIdx.x;
  if (e >= Etot) return;
  int src, dst;
  if (e < E) { src = ei[e]; dst = ei[E + e]; } else { src = e - E; dst = src; }
  int pos = atomicAdd(&cursor[dst], 1);
  srcs[pos] = src;
}

// -------- layer-1 aggregation: 32 lanes/dst, bf16 gather, 4x unroll --------
__global__ __launch_bounds__(256) void k_agg1(const int* __restrict__ rowptr,
    const int* __restrict__ srcs, const float* __restrict__ a_s,
    const float* __restrict__ a_d, const unsigned short* __restrict__ h1b,
    float* __restrict__ out1, int N) {
  int dst = (blockIdx.x*256 + threadIdx.x) >> 5;   // 32 lanes per dst
  if (dst >= N) return;
  int l = threadIdx.x & 31;
  int beg = rowptr[dst], end = rowptr[dst+1];
  int head = l >> 3;
  float ad = a_d[dst*4 + head];
  const ushort4* h4 = (const ushort4*)h1b;
  float denom = 0.f;
  float4 acc = make_float4(0.f, 0.f, 0.f, 0.f);
  int j = beg;
  for (; j + 4 <= end; j += 4) {
    int s0 = srcs[j], s1 = srcs[j+1], s2 = srcs[j+2], s3 = srcs[j+3];
    float w0 = __expf(LRELU(a_s[s0*4 + head] + ad));
    float w1 = __expf(LRELU(a_s[s1*4 + head] + ad));
    float w2 = __expf(LRELU(a_s[s2*4 + head] + ad));
    float w3 = __expf(LRELU(a_s[s3*4 + head] + ad));
    ushort4 u0 = h4[(size_t)s0*32 + l];
    ushort4 u1 = h4[(size_t)s1*32 + l];
    ushort4 u2 = h4[(size_t)s2*32 + l];
    ushort4 u3 = h4[(size_t)s3*32 + l];
    denom += (w0 + w1) + (w2 + w3);
    acc.x += w0*bf2f(u0.x) + w1*bf2f(u1.x) + w2*bf2f(u2.x) + w3*bf2f(u3.x);
    acc.y += w0*bf2f(u0.y) + w1*bf2f(u1.y) + w2*bf2f(u2.y) + w3*bf2f(u3.y);
    acc.z += w0*bf2f(u0.z) + w1*bf2f(u1.z) + w2*bf2f(u2.z) + w3*bf2f(u3.z);
    acc.w += w0*bf2f(u0.w) + w1*bf2f(u1.w) + w2*bf2f(u2.w) + w3*bf2f(u3.w);
  }
  for (; j < end; ++j) {
    int s = srcs[j];
    float w = __expf(LRELU(a_s[s*4 + head] + ad));
    ushort4 u = h4[(size_t)s*32 + l];
    denom += w;
    acc.x += w*bf2f(u.x); acc.y += w*bf2f(u.y);
    acc.z += w*bf2f(u.z); acc.w += w*bf2f(u.w);
  }
  float inv = 1.0f / (denom + 1e-16f);
  ((float4*)out1)[(size_t)dst*32 + l] =
      make_float4(acc.x*inv, acc.y*inv, acc.z*inv, acc.w*inv);
}

// ---------------- GEMM2 + attention scalars layer 2 ----------------
__global__ __launch_bounds__(320) void k_gemm2(const float* __restrict__ out1,
    const float* __restrict__ b1, const float* __restrict__ W2,
    const float* __restrict__ atts2, const float* __restrict__ attd2,
    float* __restrict__ g, float* __restrict__ a_s2, float* __restrict__ a_d2, int N) {
  __shared__ float h2s[32*130];      // stride 130: kills the stride-128 bank conflict
  __shared__ float W2s[1280];
  __shared__ float gs[320];
  int t = threadIdx.x;
  int n0 = blockIdx.x * 32;
  for (int f = t; f < 1280; f += 320) W2s[f] = W2[f];
  for (int f = t; f < 4096; f += 320) {
    int row = f >> 7, col = f & 127;
    int n = n0 + row;
    float v = 0.f;
    if (n < N) {
      v = out1[(size_t)n*128 + col] + b1[col];
      v = v > 0.f ? v : expm1f(v);
    }
    h2s[row*130 + col] = v;
  }
  __syncthreads();
  int nl = t / 10, col = t - nl*10;
  float acc = 0.f;
  #pragma unroll 8
  for (int k = 0; k < 128; ++k)
    acc += h2s[nl*130 + k] * W2s[k*10 + col];
  gs[t] = acc;
  int n = n0 + nl;
  if (n < N) g[(size_t)n*10 + col] = acc;
  __syncthreads();
  if (t < 32 && n0 + t < N) {
    float as = 0.f, ad = 0.f;
    #pragma unroll
    for (int c = 0; c < 10; ++c) {
      float gv = gs[t*10 + c];
      as += gv * atts2[c];
      ad += gv * attd2[c];
    }
    a_s2[n0 + t] = as;
    a_d2[n0 + t] = ad;
  }
}

// -------- layer-2 aggregation: 16 lanes/dst, single-pass softmax, 4x unroll --------
__global__ __launch_bounds__(256) void k_agg2(const int* __restrict__ rowptr,
    const int* __restrict__ srcs, const float* __restrict__ a_s,
    const float* __restrict__ a_d, const float* __restrict__ g,
    float* __restrict__ out2, int N) {
  int dst = (blockIdx.x*256 + threadIdx.x) >> 4;
  if (dst >= N) return;
  int l = threadIdx.x & 15;
  int beg = rowptr[dst], end = rowptr[dst+1];
  float ad = a_d[dst];
  float denom = 0.f;
  float acc = 0.f;
  bool act = (l < 10);
  int li = act ? l : 0;
  int j = beg;
  for (; j + 4 <= end; j += 4) {
    int s0 = srcs[j], s1 = srcs[j+1], s2 = srcs[j+2], s3 = srcs[j+3];
    float w0 = __expf(LRELU(a_s[s0] + ad));
    float w1 = __expf(LRELU(a_s[s1] + ad));
    float w2 = __expf(LRELU(a_s[s2] + ad));
    float w3 = __expf(LRELU(a_s[s3] + ad));
    float g0 = g[(size_t)s0*10 + li];
    float g1 = g[(size_t)s1*10 + li];
    float g2 = g[(size_t)s2*10 + li];
    float g3 = g[(size_t)s3*10 + li];
    denom += (w0 + w1) + (w2 + w3);
    acc += w0*g0 + w1*g1 + w2*g2 + w3*g3;
  }
  for (; j < end; ++j) {
    int s = srcs[j];
    float w = __expf(LRELU(a_s[s] + ad));
    float gv = g[(size_t)s*10 + li];
    denom += w;
    acc += w*gv;
  }
  if (act) out2[(size_t)dst*10 + l] = acc / (denom + 1e-16f);
}

// ---------------- final: elu(out2+b2), pool by graph (LDS-reduced) ----------------
__global__ __launch_bounds__(256) void k_final(const float* __restrict__ out2,
    const float* __restrict__ b2, const int* __restrict__ batch,
    float* __restrict__ pooled, float* __restrict__ cnt, int N) {
  __shared__ float lp[8*10];
  __shared__ float lc[8];
  __shared__ int b0s;
  int t = threadIdx.x;
  int n = blockIdx.x*256 + t;
  if (t < 80) lp[t] = 0.f;
  if (t < 8) lc[t] = 0.f;
  if (t == 0) {
    int i0 = (int)blockIdx.x * 256;
    if (i0 > N - 1) i0 = N - 1;
    b0s = batch[i0];
  }
  __syncthreads();
  int b0 = b0s;
  if (n < N) {
    int b = batch[n];
    int bl = b - b0;
    if (bl < 8) {
      #pragma unroll
      for (int c = 0; c < 10; ++c) {
        float o = out2[(size_t)n*10 + c] + b2[c];
        o = o > 0.f ? o : expm1f(o);
        atomicAdd(&lp[bl*10 + c], o);
      }
      atomicAdd(&lc[bl], 1.0f);
    } else {
      #pragma unroll
      for (int c = 0; c < 10; ++c) {
        float o = out2[(size_t)n*10 + c] + b2[c];
        o = o > 0.f ? o : expm1f(o);
        atomicAdd(&pooled[b*10 + c], o);
      }
      atomicAdd(&cnt[b], 1.0f);
    }
  }
  __syncthreads();
  if (t < 80) {
    int bl = t / 10, c = t - bl*10;
    int b = b0 + bl;
    if (b < 128 && lp[t] != 0.f) atomicAdd(&pooled[b*10 + c], lp[t]);
  }
  if (t < 8) {
    int b = b0 + t;
    if (b < 128 && lc[t] != 0.f) atomicAdd(&cnt[b], lc[t]);
  }
}

__global__ __launch_bounds__(128) void k_softmax(const float* __restrict__ pooled,
    const float* __restrict__ cnt, float* __restrict__ out) {
  int t = threadIdx.x;
  float inv = 1.0f / fmaxf(cnt[t], 1.0f);
  float v[10], m = -1e30f;
  #pragma unroll
  for (int c = 0; c < 10; ++c) { v[c] = pooled[t*10 + c] * inv; m = fmaxf(m, v[c]); }
  float s = 0.f;
  #pragma unroll
  for (int c = 0; c < 10; ++c) s += __expf(v[c] - m);
  float ls = logf(s) + m;
  #pragma unroll
  for (int c = 0; c < 10; ++c) out[t*10 + c] = v[c] - ls;
}

extern "C" void kernel_launch(void* const* d_in, const int* in_sizes, int n_in,
                              void* d_out, int out_size, void* d_ws, size_t ws_size,
                              hipStream_t stream) {
  const float* x     = (const float*)d_in[0];
  const float* W1    = (const float*)d_in[1];
  const float* atts1 = (const float*)d_in[2];
  const float* attd1 = (const float*)d_in[3];
  const float* b1    = (const float*)d_in[4];
  const float* W2    = (const float*)d_in[5];
  const float* atts2 = (const float*)d_in[6];
  const float* attd2 = (const float*)d_in[7];
  const float* b2    = (const float*)d_in[8];
  const int*   ei    = (const int*)d_in[9];
  const int*   batch = (const int*)d_in[10];
  int N = in_sizes[10];
  int E = in_sizes[9] / 2;
  int Etot = E + N;

  char* base = (char*)d_ws;
  size_t off = 0;
  auto allocB = [&](size_t bytes) { void* p = (void*)(base + off); off += (bytes + 15) & ~size_t(15); return p; };

  unsigned short* h1b = (unsigned short*)allocB((size_t)N*128*sizeof(unsigned short));
  float* out1   = (float*)allocB((size_t)N*128*sizeof(float));
  float* a_s1   = (float*)allocB((size_t)N*4*sizeof(float));
  float* a_d1   = (float*)allocB((size_t)N*4*sizeof(float));
  float* g      = (float*)allocB((size_t)N*10*sizeof(float));
  float* a_s2   = (float*)allocB((size_t)N*sizeof(float));
  float* a_d2   = (float*)allocB((size_t)N*sizeof(float));
  float* out2   = (float*)allocB((size_t)N*10*sizeof(float));
  float* pooled = (float*)allocB(1280*sizeof(float));
  float* cnt    = (float*)allocB(128*sizeof(float));
  int* deg    = (int*)allocB((size_t)N*sizeof(int));
  int* rowptr = (int*)allocB((size_t)(N+1)*sizeof(int));
  int* cursor = (int*)allocB((size_t)N*sizeof(int));
  int* bsums  = (int*)allocB(128*sizeof(int));
  int* srcs   = (int*)allocB((size_t)Etot*sizeof(int));

  int nScanBlocks = (N + 1023) / 1024;

  (void)hipMemsetAsync(deg, 0, (size_t)N*sizeof(int), stream);
  (void)hipMemsetAsync(pooled, 0, 1280*sizeof(float), stream);
  (void)hipMemsetAsync(cnt, 0, 128*sizeof(float), stream);

  // CSR build
  k_hist<<<dim3((E + 255)/256), dim3(256), 0, stream>>>(ei, E, deg);
  k_scan1<<<dim3(nScanBlocks), dim3(1024), 0, stream>>>(deg, rowptr, bsums, N);
  k_scan2<<<dim3(1), dim3(128), 0, stream>>>(bsums, nScanBlocks);
  k_scan3<<<dim3((N + 255)/256), dim3(256), 0, stream>>>(rowptr, cursor, bsums, N, Etot);
  k_scatter<<<dim3((Etot + 255)/256), dim3(256), 0, stream>>>(ei, E, Etot, cursor, srcs);

  k_gemm1<<<dim3((N + 31)/32), dim3(256), 0, stream>>>(x, W1, atts1, attd1, h1b, a_s1, a_d1, N);
  k_agg1<<<dim3((N*32 + 255)/256), dim3(256), 0, stream>>>(rowptr, srcs, a_s1, a_d1, h1b, out1, N);

  k_gemm2<<<dim3((N + 31)/32), dim3(320), 0, stream>>>(out1, b1, W2, atts2, attd2, g, a_s2, a_d2, N);
  k_agg2<<<dim3((N*16 + 255)/256), dim3(256), 0, stream>>>(rowptr, srcs, a_s2, a_d2, g, out2, N);

  k_final<<<dim3((N + 255)/256), dim3(256), 0, stream>>>(out2, b2, batch, pooled, cnt, N);
  k_softmax<<<dim3(1), dim3(128), 0, stream>>>(pooled, cnt, (float*)d_out);
}

// Round 6
// 464.633 us; speedup vs baseline: 8.7937x; 1.0998x over previous
//
#include <hip/hip_runtime.h>
#include <cstdint>
#include <cstddef>

#define LRELU(x) fmaxf((x), 0.2f*(x))

__device__ inline unsigned short f2bf(float f) {
  unsigned u = __float_as_uint(f);
  u += 0x8000u;
  return (unsigned short)(u >> 16);
}
__device__ inline float bf2f(unsigned short s) {
  return __uint_as_float((unsigned)s << 16);
}

// ------- GEMM1: h1b[N,128](bf16) = x @ W1, fused f32 a_s1/a_d1 epilogue -------
__global__ __launch_bounds__(256) void k_gemm1(const float* __restrict__ x,
                                               const float* __restrict__ W1,
                                               const float* __restrict__ atts1,
                                               const float* __restrict__ attd1,
                                               unsigned short* __restrict__ h1b,
                                               float* __restrict__ a_s, float* __restrict__ a_d,
                                               int N) {
  __shared__ float Ws[64*128];
  __shared__ float xs[32*132];
  int t = threadIdx.x;
  int n0 = blockIdx.x * 32;
  const float4* W4 = (const float4*)W1;
  const float4* x4 = (const float4*)x;
  float4* Ws4 = (float4*)Ws;
  int cg = t & 31;
  int ng = t >> 5;
  float acc[4][4] = {};
  for (int p = 0; p < 2; ++p) {
    for (int i = 0; i < 8; ++i) {
      int idx = t + i*256;
      Ws4[idx] = W4[p*2048 + idx];
    }
    if (p == 0) {
      for (int i = 0; i < 4; ++i) {
        int idx = t + i*256;
        int row = idx >> 5, c4 = idx & 31;
        int nrow = n0 + row; if (nrow >= N) nrow = N - 1;
        float4 v = x4[(size_t)nrow*32 + c4];
        float* dst = &xs[row*132 + c4*4];
        dst[0] = v.x; dst[1] = v.y; dst[2] = v.z; dst[3] = v.w;
      }
    }
    __syncthreads();
    #pragma unroll 4
    for (int k = 0; k < 64; ++k) {
      float4 wv = Ws4[k*32 + cg];
      int kk = p*64 + k;
      float xv0 = xs[(ng*4+0)*132 + kk];
      float xv1 = xs[(ng*4+1)*132 + kk];
      float xv2 = xs[(ng*4+2)*132 + kk];
      float xv3 = xs[(ng*4+3)*132 + kk];
      acc[0][0] += xv0*wv.x; acc[0][1] += xv0*wv.y; acc[0][2] += xv0*wv.z; acc[0][3] += xv0*wv.w;
      acc[1][0] += xv1*wv.x; acc[1][1] += xv1*wv.y; acc[1][2] += xv1*wv.z; acc[1][3] += xv1*wv.w;
      acc[2][0] += xv2*wv.x; acc[2][1] += xv2*wv.y; acc[2][2] += xv2*wv.z; acc[2][3] += xv2*wv.w;
      acc[3][0] += xv3*wv.x; acc[3][1] += xv3*wv.y; acc[3][2] += xv3*wv.z; acc[3][3] += xv3*wv.w;
    }
    __syncthreads();
  }
  float4 as4 = ((const float4*)atts1)[cg];
  float4 ad4 = ((const float4*)attd1)[cg];
  int head = cg >> 3;
  #pragma unroll
  for (int i = 0; i < 4; ++i) {
    int n = n0 + ng*4 + i;
    if (n < N) {
      float4 o = make_float4(acc[i][0], acc[i][1], acc[i][2], acc[i][3]);
      ushort4 hb;
      hb.x = f2bf(o.x); hb.y = f2bf(o.y); hb.z = f2bf(o.z); hb.w = f2bf(o.w);
      ((ushort4*)h1b)[(size_t)n*32 + cg] = hb;
      float ps = o.x*as4.x + o.y*as4.y + o.z*as4.z + o.w*as4.w;
      float pd = o.x*ad4.x + o.y*ad4.y + o.z*ad4.z + o.w*ad4.w;
      #pragma unroll
      for (int off = 4; off > 0; off >>= 1) {
        ps += __shfl_xor(ps, off, 8);
        pd += __shfl_xor(pd, off, 8);
      }
      if ((cg & 7) == 0) {
        a_s[n*4 + head] = ps;
        a_d[n*4 + head] = pd;
      }
    }
  }
}

// -------- CSR build, XCD-sharded (shard = blockIdx & 7 heuristic) --------
// deg_s / cursor / SP are shard-major: index s*N + dst.
__global__ __launch_bounds__(256) void k_hist_sh(const int* __restrict__ ei, int E, int Etot,
                                                 int N, int* __restrict__ deg_s) {
  int e = blockIdx.x*256 + threadIdx.x;
  if (e >= Etot) return;
  int s = blockIdx.x & 7;
  int dst = (e < E) ? ei[E + e] : (e - E);
  atomicAdd(&deg_s[s*N + dst], 1);
}

// generic block-scan over M ints: vout = exclusive-within-block, bsums = block totals
__global__ __launch_bounds__(1024) void k_scan1(const int* __restrict__ vin,
    int* __restrict__ vout, int* __restrict__ bsums, int M) {
  __shared__ int s[1024];
  int t = threadIdx.x;
  int i = blockIdx.x*1024 + t;
  int v = (i < M) ? vin[i] : 0;
  s[t] = v;
  __syncthreads();
  int val = v;
  for (int off = 1; off < 1024; off <<= 1) {
    int add = (t >= off) ? s[t - off] : 0;
    __syncthreads();
    val += add;
    s[t] = val;
    __syncthreads();
  }
  if (i < M) vout[i] = val - v;
  if (t == 1023) bsums[blockIdx.x] = val;
}

// variant: input = sum over 8 shards of deg_s
__global__ __launch_bounds__(1024) void k_scanB1(const int* __restrict__ deg_s,
    int* __restrict__ vout, int* __restrict__ bsums, int N) {
  __shared__ int s[1024];
  int t = threadIdx.x;
  int i = blockIdx.x*1024 + t;
  int v = 0;
  if (i < N) {
    #pragma unroll
    for (int sh = 0; sh < 8; ++sh) v += deg_s[sh*N + i];
  }
  s[t] = v;
  __syncthreads();
  int val = v;
  for (int off = 1; off < 1024; off <<= 1) {
    int add = (t >= off) ? s[t - off] : 0;
    __syncthreads();
    val += add;
    s[t] = val;
    __syncthreads();
  }
  if (i < N) vout[i] = val - v;
  if (t == 1023) bsums[blockIdx.x] = val;
}

__global__ __launch_bounds__(1024) void k_scan2(int* __restrict__ bsums, int nb) {
  __shared__ int s[1024];
  int t = threadIdx.x;
  int v = (t < nb) ? bsums[t] : 0;
  s[t] = v;
  __syncthreads();
  int val = v;
  for (int off = 1; off < 1024; off <<= 1) {
    int add = (t >= off) ? s[t - off] : 0;
    __syncthreads();
    val += add;
    s[t] = val;
    __syncthreads();
  }
  if (t < nb) bsums[t] = val - v;
}

__global__ __launch_bounds__(256) void k_scan3A(int* __restrict__ SP,
    int* __restrict__ cursor, const int* __restrict__ bsums, int M, int total) {
  int i = blockIdx.x*256 + threadIdx.x;
  if (i < M) {
    int r = SP[i] + bsums[i >> 10];
    SP[i] = r;
    cursor[i] = r;
  }
  if (i == 0) SP[M] = total;
}

__global__ __launch_bounds__(256) void k_scan3B(int* __restrict__ rowptr,
    const int* __restrict__ bsums, int M, int total) {
  int i = blockIdx.x*256 + threadIdx.x;
  if (i < M) rowptr[i] = rowptr[i] + bsums[i >> 10];
  if (i == 0) rowptr[M] = total;
}

__global__ __launch_bounds__(256) void k_scatter_sh(const int* __restrict__ ei, int E, int Etot,
    int N, int* __restrict__ cursor, int* __restrict__ srcs_sh) {
  int e = blockIdx.x*256 + threadIdx.x;
  if (e >= Etot) return;
  int s = blockIdx.x & 7;
  int src, dst;
  if (e < E) { src = ei[e]; dst = ei[E + e]; } else { src = e - E; dst = src; }
  int pos = atomicAdd(&cursor[s*N + dst], 1);
  srcs_sh[pos] = src;
}

// compact shard-major srcs_sh into dst-major srcs; 8 lanes per dst
__global__ __launch_bounds__(256) void k_compact(const int* __restrict__ SP,
    const int* __restrict__ rowptr, const int* __restrict__ srcs_sh,
    int* __restrict__ srcs, int N) {
  int tid = blockIdx.x*256 + threadIdx.x;
  int dst = tid >> 3;
  if (dst >= N) return;
  int s = tid & 7;
  int bg = SP[s*N + dst];
  int cnt = SP[s*N + dst + 1] - bg;   // flatten-contiguous: end(s,dst)=start of next ✓
  int incl = cnt;
  #pragma unroll
  for (int d = 1; d < 8; d <<= 1) {
    int o = __shfl_up(incl, d, 8);
    if (s >= d) incl += o;
  }
  int base = rowptr[dst] + (incl - cnt);
  for (int k = 0; k < cnt; ++k) srcs[base + k] = srcs_sh[bg + k];
}

// -------- layer-1 aggregation: 32 lanes/dst, bf16 gather, 4x unroll --------
__global__ __launch_bounds__(256) void k_agg1(const int* __restrict__ rowptr,
    const int* __restrict__ srcs, const float* __restrict__ a_s,
    const float* __restrict__ a_d, const unsigned short* __restrict__ h1b,
    float* __restrict__ out1, int N) {
  int dst = (blockIdx.x*256 + threadIdx.x) >> 5;
  if (dst >= N) return;
  int l = threadIdx.x & 31;
  int beg = rowptr[dst], end = rowptr[dst+1];
  int head = l >> 3;
  float ad = a_d[dst*4 + head];
  const ushort4* h4 = (const ushort4*)h1b;
  float denom = 0.f;
  float4 acc = make_float4(0.f, 0.f, 0.f, 0.f);
  int j = beg;
  for (; j + 4 <= end; j += 4) {
    int s0 = srcs[j], s1 = srcs[j+1], s2 = srcs[j+2], s3 = srcs[j+3];
    float w0 = __expf(LRELU(a_s[s0*4 + head] + ad));
    float w1 = __expf(LRELU(a_s[s1*4 + head] + ad));
    float w2 = __expf(LRELU(a_s[s2*4 + head] + ad));
    float w3 = __expf(LRELU(a_s[s3*4 + head] + ad));
    ushort4 u0 = h4[(size_t)s0*32 + l];
    ushort4 u1 = h4[(size_t)s1*32 + l];
    ushort4 u2 = h4[(size_t)s2*32 + l];
    ushort4 u3 = h4[(size_t)s3*32 + l];
    denom += (w0 + w1) + (w2 + w3);
    acc.x += w0*bf2f(u0.x) + w1*bf2f(u1.x) + w2*bf2f(u2.x) + w3*bf2f(u3.x);
    acc.y += w0*bf2f(u0.y) + w1*bf2f(u1.y) + w2*bf2f(u2.y) + w3*bf2f(u3.y);
    acc.z += w0*bf2f(u0.z) + w1*bf2f(u1.z) + w2*bf2f(u2.z) + w3*bf2f(u3.z);
    acc.w += w0*bf2f(u0.w) + w1*bf2f(u1.w) + w2*bf2f(u2.w) + w3*bf2f(u3.w);
  }
  for (; j < end; ++j) {
    int s = srcs[j];
    float w = __expf(LRELU(a_s[s*4 + head] + ad));
    ushort4 u = h4[(size_t)s*32 + l];
    denom += w;
    acc.x += w*bf2f(u.x); acc.y += w*bf2f(u.y);
    acc.z += w*bf2f(u.z); acc.w += w*bf2f(u.w);
  }
  float inv = 1.0f / (denom + 1e-16f);
  ((float4*)out1)[(size_t)dst*32 + l] =
      make_float4(acc.x*inv, acc.y*inv, acc.z*inv, acc.w*inv);
}

// ---------------- GEMM2 + attention scalars layer 2 ----------------
__global__ __launch_bounds__(320) void k_gemm2(const float* __restrict__ out1,
    const float* __restrict__ b1, const float* __restrict__ W2,
    const float* __restrict__ atts2, const float* __restrict__ attd2,
    float* __restrict__ g, float* __restrict__ a_s2, float* __restrict__ a_d2, int N) {
  __shared__ float h2s[32*130];
  __shared__ float W2s[1280];
  __shared__ float gs[320];
  int t = threadIdx.x;
  int n0 = blockIdx.x * 32;
  for (int f = t; f < 1280; f += 320) W2s[f] = W2[f];
  for (int f = t; f < 4096; f += 320) {
    int row = f >> 7, col = f & 127;
    int n = n0 + row;
    float v = 0.f;
    if (n < N) {
      v = out1[(size_t)n*128 + col] + b1[col];
      v = v > 0.f ? v : expm1f(v);
    }
    h2s[row*130 + col] = v;
  }
  __syncthreads();
  int nl = t / 10, col = t - nl*10;
  float acc = 0.f;
  #pragma unroll 8
  for (int k = 0; k < 128; ++k)
    acc += h2s[nl*130 + k] * W2s[k*10 + col];
  gs[t] = acc;
  int n = n0 + nl;
  if (n < N) g[(size_t)n*10 + col] = acc;
  __syncthreads();
  if (t < 32 && n0 + t < N) {
    float as = 0.f, ad = 0.f;
    #pragma unroll
    for (int c = 0; c < 10; ++c) {
      float gv = gs[t*10 + c];
      as += gv * atts2[c];
      ad += gv * attd2[c];
    }
    a_s2[n0 + t] = as;
    a_d2[n0 + t] = ad;
  }
}

// -------- layer-2 aggregation: 16 lanes/dst, single-pass softmax, 4x unroll --------
__global__ __launch_bounds__(256) void k_agg2(const int* __restrict__ rowptr,
    const int* __restrict__ srcs, const float* __restrict__ a_s,
    const float* __restrict__ a_d, const float* __restrict__ g,
    float* __restrict__ out2, int N) {
  int dst = (blockIdx.x*256 + threadIdx.x) >> 4;
  if (dst >= N) return;
  int l = threadIdx.x & 15;
  int beg = rowptr[dst], end = rowptr[dst+1];
  float ad = a_d[dst];
  float denom = 0.f;
  float acc = 0.f;
  bool act = (l < 10);
  int li = act ? l : 0;
  int j = beg;
  for (; j + 4 <= end; j += 4) {
    int s0 = srcs[j], s1 = srcs[j+1], s2 = srcs[j+2], s3 = srcs[j+3];
    float w0 = __expf(LRELU(a_s[s0] + ad));
    float w1 = __expf(LRELU(a_s[s1] + ad));
    float w2 = __expf(LRELU(a_s[s2] + ad));
    float w3 = __expf(LRELU(a_s[s3] + ad));
    float g0 = g[(size_t)s0*10 + li];
    float g1 = g[(size_t)s1*10 + li];
    float g2 = g[(size_t)s2*10 + li];
    float g3 = g[(size_t)s3*10 + li];
    denom += (w0 + w1) + (w2 + w3);
    acc += w0*g0 + w1*g1 + w2*g2 + w3*g3;
  }
  for (; j < end; ++j) {
    int s = srcs[j];
    float w = __expf(LRELU(a_s[s] + ad));
    float gv = g[(size_t)s*10 + li];
    denom += w;
    acc += w*gv;
  }
  if (act) out2[(size_t)dst*10 + l] = acc / (denom + 1e-16f);
}

// ---------------- final: elu(out2+b2), pool by graph (LDS-reduced) ----------------
__global__ __launch_bounds__(256) void k_final(const float* __restrict__ out2,
    const float* __restrict__ b2, const int* __restrict__ batch,
    float* __restrict__ pooled, float* __restrict__ cnt, int N) {
  __shared__ float lp[8*10];
  __shared__ float lc[8];
  __shared__ int b0s;
  int t = threadIdx.x;
  int n = blockIdx.x*256 + t;
  if (t < 80) lp[t] = 0.f;
  if (t < 8) lc[t] = 0.f;
  if (t == 0) {
    int i0 = (int)blockIdx.x * 256;
    if (i0 > N - 1) i0 = N - 1;
    b0s = batch[i0];
  }
  __syncthreads();
  int b0 = b0s;
  if (n < N) {
    int b = batch[n];
    int bl = b - b0;
    if (bl < 8) {
      #pragma unroll
      for (int c = 0; c < 10; ++c) {
        float o = out2[(size_t)n*10 + c] + b2[c];
        o = o > 0.f ? o : expm1f(o);
        atomicAdd(&lp[bl*10 + c], o);
      }
      atomicAdd(&lc[bl], 1.0f);
    } else {
      #pragma unroll
      for (int c = 0; c < 10; ++c) {
        float o = out2[(size_t)n*10 + c] + b2[c];
        o = o > 0.f ? o : expm1f(o);
        atomicAdd(&pooled[b*10 + c], o);
      }
      atomicAdd(&cnt[b], 1.0f);
    }
  }
  __syncthreads();
  if (t < 80) {
    int bl = t / 10, c = t - bl*10;
    int b = b0 + bl;
    if (b < 128 && lp[t] != 0.f) atomicAdd(&pooled[b*10 + c], lp[t]);
  }
  if (t < 8) {
    int b = b0 + t;
    if (b < 128 && lc[t] != 0.f) atomicAdd(&cnt[b], lc[t]);
  }
}

__global__ __launch_bounds__(128) void k_softmax(const float* __restrict__ pooled,
    const float* __restrict__ cnt, float* __restrict__ out) {
  int t = threadIdx.x;
  float inv = 1.0f / fmaxf(cnt[t], 1.0f);
  float v[10], m = -1e30f;
  #pragma unroll
  for (int c = 0; c < 10; ++c) { v[c] = pooled[t*10 + c] * inv; m = fmaxf(m, v[c]); }
  float s = 0.f;
  #pragma unroll
  for (int c = 0; c < 10; ++c) s += __expf(v[c] - m);
  float ls = logf(s) + m;
  #pragma unroll
  for (int c = 0; c < 10; ++c) out[t*10 + c] = v[c] - ls;
}

extern "C" void kernel_launch(void* const* d_in, const int* in_sizes, int n_in,
                              void* d_out, int out_size, void* d_ws, size_t ws_size,
                              hipStream_t stream) {
  const float* x     = (const float*)d_in[0];
  const float* W1    = (const float*)d_in[1];
  const float* atts1 = (const float*)d_in[2];
  const float* attd1 = (const float*)d_in[3];
  const float* b1    = (const float*)d_in[4];
  const float* W2    = (const float*)d_in[5];
  const float* atts2 = (const float*)d_in[6];
  const float* attd2 = (const float*)d_in[7];
  const float* b2    = (const float*)d_in[8];
  const int*   ei    = (const int*)d_in[9];
  const int*   batch = (const int*)d_in[10];
  int N = in_sizes[10];
  int E = in_sizes[9] / 2;
  int Etot = E + N;
  int M8 = 8 * N;

  char* base = (char*)d_ws;
  size_t off = 0;
  auto allocB = [&](size_t bytes) { void* p = (void*)(base + off); off += (bytes + 63) & ~size_t(63); return p; };

  unsigned short* h1b = (unsigned short*)allocB((size_t)N*128*sizeof(unsigned short));
  float* out1   = (float*)allocB((size_t)N*128*sizeof(float));
  float* a_s1   = (float*)allocB((size_t)N*4*sizeof(float));
  float* a_d1   = (float*)allocB((size_t)N*4*sizeof(float));
  float* g      = (float*)allocB((size_t)N*10*sizeof(float));
  float* a_s2   = (float*)allocB((size_t)N*sizeof(float));
  float* a_d2   = (float*)allocB((size_t)N*sizeof(float));
  float* out2   = (float*)allocB((size_t)N*10*sizeof(float));
  float* pooled = (float*)allocB(1280*sizeof(float));
  float* cnt    = (float*)allocB(128*sizeof(float));
  int* deg_s  = (int*)allocB((size_t)M8*sizeof(int));
  int* SP     = (int*)allocB((size_t)(M8+1)*sizeof(int));
  int* cursor = (int*)allocB((size_t)M8*sizeof(int));
  int* rowptr = (int*)allocB((size_t)(N+1)*sizeof(int));
  int* bsumsA = (int*)allocB(1024*sizeof(int));
  int* bsumsB = (int*)allocB(1024*sizeof(int));
  int* srcs_sh= (int*)allocB((size_t)Etot*sizeof(int));
  int* srcs   = (int*)allocB((size_t)Etot*sizeof(int));

  int nbA = (M8 + 1023) / 1024;   // 782 for N=100k (<=1024 ok)
  int nbB = (N + 1023) / 1024;    // 98

  (void)hipMemsetAsync(deg_s, 0, (size_t)M8*sizeof(int), stream);
  (void)hipMemsetAsync(pooled, 0, 1280*sizeof(float), stream);
  (void)hipMemsetAsync(cnt, 0, 128*sizeof(float), stream);

  // sharded CSR build
  k_hist_sh<<<dim3((Etot + 255)/256), dim3(256), 0, stream>>>(ei, E, Etot, N, deg_s);
  k_scan1<<<dim3(nbA), dim3(1024), 0, stream>>>(deg_s, SP, bsumsA, M8);
  k_scan2<<<dim3(1), dim3(1024), 0, stream>>>(bsumsA, nbA);
  k_scan3A<<<dim3((M8 + 255)/256), dim3(256), 0, stream>>>(SP, cursor, bsumsA, M8, Etot);
  k_scatter_sh<<<dim3((Etot + 255)/256), dim3(256), 0, stream>>>(ei, E, Etot, N, cursor, srcs_sh);
  k_scanB1<<<dim3(nbB), dim3(1024), 0, stream>>>(deg_s, rowptr, bsumsB, N);
  k_scan2<<<dim3(1), dim3(1024), 0, stream>>>(bsumsB, nbB);
  k_scan3B<<<dim3((N + 255)/256), dim3(256), 0, stream>>>(rowptr, bsumsB, N, Etot);
  k_compact<<<dim3((N*8 + 255)/256), dim3(256), 0, stream>>>(SP, rowptr, srcs_sh, srcs, N);

  k_gemm1<<<dim3((N + 31)/32), dim3(256), 0, stream>>>(x, W1, atts1, attd1, h1b, a_s1, a_d1, N);
  k_agg1<<<dim3((N*32 + 255)/256), dim3(256), 0, stream>>>(rowptr, srcs, a_s1, a_d1, h1b, out1, N);

  k_gemm2<<<dim3((N + 31)/32), dim3(320), 0, stream>>>(out1, b1, W2, atts2, attd2, g, a_s2, a_d2, N);
  k_agg2<<<dim3((N*16 + 255)/256), dim3(256), 0, stream>>>(rowptr, srcs, a_s2, a_d2, g, out2, N);

  k_final<<<dim3((N + 255)/256), dim3(256), 0, stream>>>(out2, b2, batch, pooled, cnt, N);
  k_softmax<<<dim3(1), dim3(128), 0, stream>>>(pooled, cnt, (float*)d_out);
}

// Round 7
// 458.053 us; speedup vs baseline: 8.9200x; 1.0144x over previous
//
#include <hip/hip_runtime.h>
#include <cstdint>
#include <cstddef>

#define LRELU(x) fmaxf((x), 0.2f*(x))

__device__ inline unsigned short f2bf(float f) {
  unsigned u = __float_as_uint(f);
  u += 0x8000u;
  return (unsigned short)(u >> 16);
}
__device__ inline float bf2f(unsigned short s) {
  return __uint_as_float((unsigned)s << 16);
}

// ------- GEMM1: h1b[N,128](bf16) = x @ W1, fused f32 a_s1/a_d1 epilogue -------
__global__ __launch_bounds__(256) void k_gemm1(const float* __restrict__ x,
                                               const float* __restrict__ W1,
                                               const float* __restrict__ atts1,
                                               const float* __restrict__ attd1,
                                               unsigned short* __restrict__ h1b,
                                               float* __restrict__ a_s, float* __restrict__ a_d,
                                               int N) {
  __shared__ float Ws[64*128];
  __shared__ float xs[32*132];
  int t = threadIdx.x;
  int n0 = blockIdx.x * 32;
  const float4* W4 = (const float4*)W1;
  const float4* x4 = (const float4*)x;
  float4* Ws4 = (float4*)Ws;
  int cg = t & 31;
  int ng = t >> 5;
  float acc[4][4] = {};
  for (int p = 0; p < 2; ++p) {
    for (int i = 0; i < 8; ++i) {
      int idx = t + i*256;
      Ws4[idx] = W4[p*2048 + idx];
    }
    if (p == 0) {
      for (int i = 0; i < 4; ++i) {
        int idx = t + i*256;
        int row = idx >> 5, c4 = idx & 31;
        int nrow = n0 + row; if (nrow >= N) nrow = N - 1;
        float4 v = x4[(size_t)nrow*32 + c4];
        float* dst = &xs[row*132 + c4*4];
        dst[0] = v.x; dst[1] = v.y; dst[2] = v.z; dst[3] = v.w;
      }
    }
    __syncthreads();
    #pragma unroll 4
    for (int k = 0; k < 64; ++k) {
      float4 wv = Ws4[k*32 + cg];
      int kk = p*64 + k;
      float xv0 = xs[(ng*4+0)*132 + kk];
      float xv1 = xs[(ng*4+1)*132 + kk];
      float xv2 = xs[(ng*4+2)*132 + kk];
      float xv3 = xs[(ng*4+3)*132 + kk];
      acc[0][0] += xv0*wv.x; acc[0][1] += xv0*wv.y; acc[0][2] += xv0*wv.z; acc[0][3] += xv0*wv.w;
      acc[1][0] += xv1*wv.x; acc[1][1] += xv1*wv.y; acc[1][2] += xv1*wv.z; acc[1][3] += xv1*wv.w;
      acc[2][0] += xv2*wv.x; acc[2][1] += xv2*wv.y; acc[2][2] += xv2*wv.z; acc[2][3] += xv2*wv.w;
      acc[3][0] += xv3*wv.x; acc[3][1] += xv3*wv.y; acc[3][2] += xv3*wv.z; acc[3][3] += xv3*wv.w;
    }
    __syncthreads();
  }
  float4 as4 = ((const float4*)atts1)[cg];
  float4 ad4 = ((const float4*)attd1)[cg];
  int head = cg >> 3;
  #pragma unroll
  for (int i = 0; i < 4; ++i) {
    int n = n0 + ng*4 + i;
    if (n < N) {
      float4 o = make_float4(acc[i][0], acc[i][1], acc[i][2], acc[i][3]);
      ushort4 hb;
      hb.x = f2bf(o.x); hb.y = f2bf(o.y); hb.z = f2bf(o.z); hb.w = f2bf(o.w);
      ((ushort4*)h1b)[(size_t)n*32 + cg] = hb;
      float ps = o.x*as4.x + o.y*as4.y + o.z*as4.z + o.w*as4.w;
      float pd = o.x*ad4.x + o.y*ad4.y + o.z*ad4.z + o.w*ad4.w;
      #pragma unroll
      for (int off = 4; off > 0; off >>= 1) {
        ps += __shfl_xor(ps, off, 8);
        pd += __shfl_xor(pd, off, 8);
      }
      if ((cg & 7) == 0) {
        a_s[n*4 + head] = ps;
        a_d[n*4 + head] = pd;
      }
    }
  }
}

// -------- CSR build, XCD-sharded (shard = blockIdx & 7 heuristic) --------
__global__ __launch_bounds__(256) void k_hist_sh(const int* __restrict__ ei, int E, int Etot,
                                                 int N, int* __restrict__ deg_s) {
  int e = blockIdx.x*256 + threadIdx.x;
  if (e >= Etot) return;
  int s = blockIdx.x & 7;
  int dst = (e < E) ? ei[E + e] : (e - E);
  atomicAdd(&deg_s[s*N + dst], 1);
}

// vectorized scan: 1024 thr, 4 ints/thread -> 4096 elems/block; exclusive out
__global__ __launch_bounds__(1024) void k_scan1v(const int* __restrict__ vin,
    int* __restrict__ vout, int* __restrict__ bsums, int M) {
  __shared__ int wsum[16];
  int t = threadIdx.x;
  int lane = t & 63, wave = t >> 6;
  size_t base = (size_t)blockIdx.x*4096 + (size_t)t*4;
  int4 v = make_int4(0,0,0,0);
  if (base + 3 < (size_t)M) {
    v = *(const int4*)(vin + base);
  } else {
    if (base+0 < (size_t)M) v.x = vin[base+0];
    if (base+1 < (size_t)M) v.y = vin[base+1];
    if (base+2 < (size_t)M) v.z = vin[base+2];
    if (base+3 < (size_t)M) v.w = vin[base+3];
  }
  int s0 = v.x, s1 = s0 + v.y, s2 = s1 + v.z, tot = s2 + v.w;
  int inc = tot;
  #pragma unroll
  for (int off = 1; off < 64; off <<= 1) {
    int u = __shfl_up(inc, off, 64);
    if (lane >= off) inc += u;
  }
  if (lane == 63) wsum[wave] = inc;
  __syncthreads();
  if (t < 16) {
    int w = wsum[t];
    int iw = w;
    #pragma unroll
    for (int off = 1; off < 16; off <<= 1) {
      int u = __shfl_up(iw, off, 16);
      if (t >= off) iw += u;
    }
    wsum[t] = iw - w;   // exclusive wave offsets
    if (t == 15) bsums[blockIdx.x] = iw;   // block total
  }
  __syncthreads();
  int offb = wsum[wave] + (inc - tot);
  int4 o = make_int4(offb, offb + s0, offb + s1, offb + s2);
  if (base + 3 < (size_t)M) {
    *(int4*)(vout + base) = o;
  } else {
    if (base+0 < (size_t)M) vout[base+0] = o.x;
    if (base+1 < (size_t)M) vout[base+1] = o.y;
    if (base+2 < (size_t)M) vout[base+2] = o.z;
    if (base+3 < (size_t)M) vout[base+3] = o.w;
  }
}

// variant: element i = sum over 8 shards of deg_s
__global__ __launch_bounds__(1024) void k_scanB1v(const int* __restrict__ deg_s,
    int* __restrict__ vout, int* __restrict__ bsums, int N) {
  __shared__ int wsum[16];
  int t = threadIdx.x;
  int lane = t & 63, wave = t >> 6;
  size_t base = (size_t)blockIdx.x*4096 + (size_t)t*4;
  int4 v = make_int4(0,0,0,0);
  if (base + 3 < (size_t)N) {
    #pragma unroll
    for (int sh = 0; sh < 8; ++sh) {
      int4 d = *(const int4*)(deg_s + (size_t)sh*N + base);
      v.x += d.x; v.y += d.y; v.z += d.z; v.w += d.w;
    }
  } else {
    for (int q = 0; q < 4; ++q) {
      if (base + q < (size_t)N) {
        int sum = 0;
        for (int sh = 0; sh < 8; ++sh) sum += deg_s[(size_t)sh*N + base + q];
        if (q == 0) v.x = sum; else if (q == 1) v.y = sum;
        else if (q == 2) v.z = sum; else v.w = sum;
      }
    }
  }
  int s0 = v.x, s1 = s0 + v.y, s2 = s1 + v.z, tot = s2 + v.w;
  int inc = tot;
  #pragma unroll
  for (int off = 1; off < 64; off <<= 1) {
    int u = __shfl_up(inc, off, 64);
    if (lane >= off) inc += u;
  }
  if (lane == 63) wsum[wave] = inc;
  __syncthreads();
  if (t < 16) {
    int w = wsum[t];
    int iw = w;
    #pragma unroll
    for (int off = 1; off < 16; off <<= 1) {
      int u = __shfl_up(iw, off, 16);
      if (t >= off) iw += u;
    }
    wsum[t] = iw - w;
    if (t == 15) bsums[blockIdx.x] = iw;
  }
  __syncthreads();
  int offb = wsum[wave] + (inc - tot);
  int4 o = make_int4(offb, offb + s0, offb + s1, offb + s2);
  if (base + 3 < (size_t)N) {
    *(int4*)(vout + base) = o;
  } else {
    if (base+0 < (size_t)N) vout[base+0] = o.x;
    if (base+1 < (size_t)N) vout[base+1] = o.y;
    if (base+2 < (size_t)N) vout[base+2] = o.z;
    if (base+3 < (size_t)N) vout[base+3] = o.w;
  }
}

__global__ __launch_bounds__(1024) void k_scan2(int* __restrict__ bsums, int nb) {
  __shared__ int s[1024];
  int t = threadIdx.x;
  int v = (t < nb) ? bsums[t] : 0;
  s[t] = v;
  __syncthreads();
  int val = v;
  for (int off = 1; off < 1024; off <<= 1) {
    int add = (t >= off) ? s[t - off] : 0;
    __syncthreads();
    val += add;
    s[t] = val;
    __syncthreads();
  }
  if (t < nb) bsums[t] = val - v;
}

// NOTE: scan blocks now cover 4096 elements -> index shift 12
__global__ __launch_bounds__(256) void k_scan3A(int* __restrict__ SP,
    int* __restrict__ cursor, const int* __restrict__ bsums, int M, int total) {
  int i = blockIdx.x*256 + threadIdx.x;
  if (i < M) {
    int r = SP[i] + bsums[i >> 12];
    SP[i] = r;
    cursor[i] = r;
  }
  if (i == 0) SP[M] = total;
}

__global__ __launch_bounds__(256) void k_scan3B(int* __restrict__ rowptr,
    const int* __restrict__ bsums, int M, int total) {
  int i = blockIdx.x*256 + threadIdx.x;
  if (i < M) rowptr[i] = rowptr[i] + bsums[i >> 12];
  if (i == 0) rowptr[M] = total;
}

__global__ __launch_bounds__(256) void k_scatter_sh(const int* __restrict__ ei, int E, int Etot,
    int N, int* __restrict__ cursor, int* __restrict__ srcs_sh) {
  int e = blockIdx.x*256 + threadIdx.x;
  if (e >= Etot) return;
  int s = blockIdx.x & 7;
  int src, dst;
  if (e < E) { src = ei[e]; dst = ei[E + e]; } else { src = e - E; dst = src; }
  int pos = atomicAdd(&cursor[s*N + dst], 1);
  srcs_sh[pos] = src;
}

// compact shard-major srcs_sh into dst-major srcs; 8 lanes per dst
__global__ __launch_bounds__(256) void k_compact(const int* __restrict__ SP,
    const int* __restrict__ rowptr, const int* __restrict__ srcs_sh,
    int* __restrict__ srcs, int N) {
  int tid = blockIdx.x*256 + threadIdx.x;
  int dst = tid >> 3;
  if (dst >= N) return;
  int s = tid & 7;
  int bg = SP[s*N + dst];
  int cnt = SP[s*N + dst + 1] - bg;
  int incl = cnt;
  #pragma unroll
  for (int d = 1; d < 8; d <<= 1) {
    int o = __shfl_up(incl, d, 8);
    if (s >= d) incl += o;
  }
  int base = rowptr[dst] + (incl - cnt);
  for (int k = 0; k < cnt; ++k) srcs[base + k] = srcs_sh[bg + k];
}

// -------- layer-1 aggregation + fused GEMM2 + layer-2 attention scalars --------
// 32 lanes/dst. After aggregation: h2=elu(out1+b1) in regs, g row via butterfly,
// a_s2/a_d2 on lane 0. out1 never materialized.
__global__ __launch_bounds__(256) void k_agg1g2(const int* __restrict__ rowptr,
    const int* __restrict__ srcs, const float* __restrict__ a_s,
    const float* __restrict__ a_d, const unsigned short* __restrict__ h1b,
    const float* __restrict__ b1, const float* __restrict__ W2,
    const float* __restrict__ atts2, const float* __restrict__ attd2,
    float* __restrict__ g, float* __restrict__ a_s2, float* __restrict__ a_d2,
    int N) {
  __shared__ float W2t[1280];   // transposed: W2t[c*128 + k] = W2[k*10 + c]
  __shared__ float att2s[20];
  int t = threadIdx.x;
  for (int f = t; f < 1280; f += 256) {
    int c = f >> 7, k = f & 127;
    W2t[f] = W2[k*10 + c];
  }
  if (t < 20) att2s[t] = (t < 10) ? atts2[t] : attd2[t - 10];
  __syncthreads();

  int dst = (blockIdx.x*256 + t) >> 5;
  if (dst >= N) return;
  int l = t & 31;
  int beg = rowptr[dst], end = rowptr[dst+1];
  int head = l >> 3;
  float ad = a_d[dst*4 + head];
  const ushort4* h4 = (const ushort4*)h1b;
  float denom = 0.f;
  float4 acc = make_float4(0.f, 0.f, 0.f, 0.f);
  int j = beg;
  for (; j + 4 <= end; j += 4) {
    int s0 = srcs[j], s1 = srcs[j+1], s2 = srcs[j+2], s3 = srcs[j+3];
    float w0 = __expf(LRELU(a_s[s0*4 + head] + ad));
    float w1 = __expf(LRELU(a_s[s1*4 + head] + ad));
    float w2 = __expf(LRELU(a_s[s2*4 + head] + ad));
    float w3 = __expf(LRELU(a_s[s3*4 + head] + ad));
    ushort4 u0 = h4[(size_t)s0*32 + l];
    ushort4 u1 = h4[(size_t)s1*32 + l];
    ushort4 u2 = h4[(size_t)s2*32 + l];
    ushort4 u3 = h4[(size_t)s3*32 + l];
    denom += (w0 + w1) + (w2 + w3);
    acc.x += w0*bf2f(u0.x) + w1*bf2f(u1.x) + w2*bf2f(u2.x) + w3*bf2f(u3.x);
    acc.y += w0*bf2f(u0.y) + w1*bf2f(u1.y) + w2*bf2f(u2.y) + w3*bf2f(u3.y);
    acc.z += w0*bf2f(u0.z) + w1*bf2f(u1.z) + w2*bf2f(u2.z) + w3*bf2f(u3.z);
    acc.w += w0*bf2f(u0.w) + w1*bf2f(u1.w) + w2*bf2f(u2.w) + w3*bf2f(u3.w);
  }
  for (; j < end; ++j) {
    int s = srcs[j];
    float w = __expf(LRELU(a_s[s*4 + head] + ad));
    ushort4 u = h4[(size_t)s*32 + l];
    denom += w;
    acc.x += w*bf2f(u.x); acc.y += w*bf2f(u.y);
    acc.z += w*bf2f(u.z); acc.w += w*bf2f(u.w);
  }
  float inv = 1.0f / (denom + 1e-16f);
  float4 b14 = ((const float4*)b1)[l];
  float h0 = acc.x*inv + b14.x; h0 = h0 > 0.f ? h0 : expm1f(h0);
  float h1v = acc.y*inv + b14.y; h1v = h1v > 0.f ? h1v : expm1f(h1v);
  float h2v = acc.z*inv + b14.z; h2v = h2v > 0.f ? h2v : expm1f(h2v);
  float h3v = acc.w*inv + b14.w; h3v = h3v > 0.f ? h3v : expm1f(h3v);
  // partial g: lane holds channels 4l..4l+3; conflict-free float4 LDS reads
  const float4* W2t4 = (const float4*)W2t;
  float p[10];
  #pragma unroll
  for (int c = 0; c < 10; ++c) {
    float4 wv = W2t4[c*32 + l];
    p[c] = h0*wv.x + h1v*wv.y + h2v*wv.z + h3v*wv.w;
  }
  // butterfly over the dst's 32 lanes -> all lanes hold full g row
  #pragma unroll
  for (int off = 16; off > 0; off >>= 1) {
    #pragma unroll
    for (int c = 0; c < 10; ++c)
      p[c] += __shfl_xor(p[c], off, 32);
  }
  if (l < 10) {
    float val = p[0];
    #pragma unroll
    for (int c = 1; c < 10; ++c) val = (l == c) ? p[c] : val;
    g[(size_t)dst*10 + l] = val;
  }
  if (l == 0) {
    float as = 0.f, adv = 0.f;
    #pragma unroll
    for (int c = 0; c < 10; ++c) {
      as  += p[c]*att2s[c];
      adv += p[c]*att2s[10 + c];
    }
    a_s2[dst] = as;
    a_d2[dst] = adv;
  }
}

// -------- layer-2 aggregation fused with bias/elu/pool: 16 lanes/dst --------
__global__ __launch_bounds__(256) void k_agg2f(const int* __restrict__ rowptr,
    const int* __restrict__ srcs, const float* __restrict__ a_s,
    const float* __restrict__ a_d, const float* __restrict__ g,
    const float* __restrict__ b2, const int* __restrict__ batch,
    float* __restrict__ pooled, float* __restrict__ cnt, int N) {
  __shared__ float lp[4*10];
  __shared__ float lc[4];
  __shared__ int b0s;
  int t = threadIdx.x;
  int dst = (blockIdx.x*256 + t) >> 4;
  int l = t & 15;
  if (t < 40) lp[t] = 0.f;
  if (t < 4) lc[t] = 0.f;
  if (t == 0) {
    int d0 = (blockIdx.x*256) >> 4;
    if (d0 > N - 1) d0 = N - 1;
    b0s = batch[d0];
  }
  __syncthreads();
  int b0 = b0s;
  bool valid = (dst < N);
  float o = 0.f;
  int b = 0;
  if (valid) {
    int beg = rowptr[dst], end = rowptr[dst+1];
    float ad = a_d[dst];
    float denom = 0.f;
    float acc = 0.f;
    bool act = (l < 10);
    int li = act ? l : 0;
    int j = beg;
    for (; j + 4 <= end; j += 4) {
      int s0 = srcs[j], s1 = srcs[j+1], s2 = srcs[j+2], s3 = srcs[j+3];
      float w0 = __expf(LRELU(a_s[s0] + ad));
      float w1 = __expf(LRELU(a_s[s1] + ad));
      float w2 = __expf(LRELU(a_s[s2] + ad));
      float w3 = __expf(LRELU(a_s[s3] + ad));
      float g0 = g[(size_t)s0*10 + li];
      float g1 = g[(size_t)s1*10 + li];
      float g2 = g[(size_t)s2*10 + li];
      float g3 = g[(size_t)s3*10 + li];
      denom += (w0 + w1) + (w2 + w3);
      acc += w0*g0 + w1*g1 + w2*g2 + w3*g3;
    }
    for (; j < end; ++j) {
      int s = srcs[j];
      float w = __expf(LRELU(a_s[s] + ad));
      float gv = g[(size_t)s*10 + li];
      denom += w;
      acc += w*gv;
    }
    b = batch[dst];
    if (l < 10) {
      o = acc / (denom + 1e-16f) + b2[l];
      o = o > 0.f ? o : expm1f(o);
    }
  }
  if (valid) {
    int bl = b - b0;
    if (l < 10) {
      if (bl < 4) atomicAdd(&lp[bl*10 + l], o);
      else atomicAdd(&pooled[b*10 + l], o);
    }
    if (l == 0) {
      if (bl < 4) atomicAdd(&lc[bl], 1.0f);
      else atomicAdd(&cnt[b], 1.0f);
    }
  }
  __syncthreads();
  if (t < 40) {
    int bl = t / 10, c = t - bl*10;
    int bb = b0 + bl;
    if (bb < 128 && lp[t] != 0.f) atomicAdd(&pooled[bb*10 + c], lp[t]);
  }
  if (t < 4) {
    int bb = b0 + t;
    if (bb < 128 && lc[t] != 0.f) atomicAdd(&cnt[bb], lc[t]);
  }
}

__global__ __launch_bounds__(128) void k_softmax(const float* __restrict__ pooled,
    const float* __restrict__ cnt, float* __restrict__ out) {
  int t = threadIdx.x;
  float inv = 1.0f / fmaxf(cnt[t], 1.0f);
  float v[10], m = -1e30f;
  #pragma unroll
  for (int c = 0; c < 10; ++c) { v[c] = pooled[t*10 + c] * inv; m = fmaxf(m, v[c]); }
  float s = 0.f;
  #pragma unroll
  for (int c = 0; c < 10; ++c) s += __expf(v[c] - m);
  float ls = logf(s) + m;
  #pragma unroll
  for (int c = 0; c < 10; ++c) out[t*10 + c] = v[c] - ls;
}

extern "C" void kernel_launch(void* const* d_in, const int* in_sizes, int n_in,
                              void* d_out, int out_size, void* d_ws, size_t ws_size,
                              hipStream_t stream) {
  const float* x     = (const float*)d_in[0];
  const float* W1    = (const float*)d_in[1];
  const float* atts1 = (const float*)d_in[2];
  const float* attd1 = (const float*)d_in[3];
  const float* b1    = (const float*)d_in[4];
  const float* W2    = (const float*)d_in[5];
  const float* atts2 = (const float*)d_in[6];
  const float* attd2 = (const float*)d_in[7];
  const float* b2    = (const float*)d_in[8];
  const int*   ei    = (const int*)d_in[9];
  const int*   batch = (const int*)d_in[10];
  int N = in_sizes[10];
  int E = in_sizes[9] / 2;
  int Etot = E + N;
  int M8 = 8 * N;

  char* base = (char*)d_ws;
  size_t off = 0;
  auto allocB = [&](size_t bytes) { void* p = (void*)(base + off); off += (bytes + 63) & ~size_t(63); return p; };

  unsigned short* h1b = (unsigned short*)allocB((size_t)N*128*sizeof(unsigned short));
  float* a_s1   = (float*)allocB((size_t)N*4*sizeof(float));
  float* a_d1   = (float*)allocB((size_t)N*4*sizeof(float));
  float* g      = (float*)allocB((size_t)N*10*sizeof(float));
  float* a_s2   = (float*)allocB((size_t)N*sizeof(float));
  float* a_d2   = (float*)allocB((size_t)N*sizeof(float));
  float* pooled = (float*)allocB(1280*sizeof(float));
  float* cnt    = (float*)allocB(128*sizeof(float));
  int* deg_s  = (int*)allocB((size_t)M8*sizeof(int));
  int* SP     = (int*)allocB((size_t)(M8+1)*sizeof(int));
  int* cursor = (int*)allocB((size_t)M8*sizeof(int));
  int* rowptr = (int*)allocB((size_t)(N+1)*sizeof(int));
  int* bsumsA = (int*)allocB(1024*sizeof(int));
  int* bsumsB = (int*)allocB(1024*sizeof(int));
  int* srcs_sh= (int*)allocB((size_t)Etot*sizeof(int));
  int* srcs   = (int*)allocB((size_t)Etot*sizeof(int));

  int nbA = (M8 + 4095) / 4096;   // 196 for N=100k
  int nbB = (N + 4095) / 4096;    // 25

  (void)hipMemsetAsync(deg_s, 0, (size_t)M8*sizeof(int), stream);
  (void)hipMemsetAsync(pooled, 0, 1280*sizeof(float), stream);
  (void)hipMemsetAsync(cnt, 0, 128*sizeof(float), stream);

  // sharded CSR build
  k_hist_sh<<<dim3((Etot + 255)/256), dim3(256), 0, stream>>>(ei, E, Etot, N, deg_s);
  k_scan1v<<<dim3(nbA), dim3(1024), 0, stream>>>(deg_s, SP, bsumsA, M8);
  k_scan2<<<dim3(1), dim3(1024), 0, stream>>>(bsumsA, nbA);
  k_scan3A<<<dim3((M8 + 255)/256), dim3(256), 0, stream>>>(SP, cursor, bsumsA, M8, Etot);
  k_scatter_sh<<<dim3((Etot + 255)/256), dim3(256), 0, stream>>>(ei, E, Etot, N, cursor, srcs_sh);
  k_scanB1v<<<dim3(nbB), dim3(1024), 0, stream>>>(deg_s, rowptr, bsumsB, N);
  k_scan2<<<dim3(1), dim3(1024), 0, stream>>>(bsumsB, nbB);
  k_scan3B<<<dim3((N + 255)/256), dim3(256), 0, stream>>>(rowptr, bsumsB, N, Etot);
  k_compact<<<dim3((N*8 + 255)/256), dim3(256), 0, stream>>>(SP, rowptr, srcs_sh, srcs, N);

  k_gemm1<<<dim3((N + 31)/32), dim3(256), 0, stream>>>(x, W1, atts1, attd1, h1b, a_s1, a_d1, N);
  k_agg1g2<<<dim3((N*32 + 255)/256), dim3(256), 0, stream>>>(rowptr, srcs, a_s1, a_d1, h1b,
                                                             b1, W2, atts2, attd2,
                                                             g, a_s2, a_d2, N);
  k_agg2f<<<dim3((N*16 + 255)/256), dim3(256), 0, stream>>>(rowptr, srcs, a_s2, a_d2, g,
                                                            b2, batch, pooled, cnt, N);
  k_softmax<<<dim3(1), dim3(128), 0, stream>>>(pooled, cnt, (float*)d_out);
}

// Round 8
// 444.686 us; speedup vs baseline: 9.1881x; 1.0301x over previous
//
#include <hip/hip_runtime.h>
#include <cstdint>
#include <cstddef>

#define LRELU(x) fmaxf((x), 0.2f*(x))

typedef float v2f __attribute__((ext_vector_type(2)));

// ------- GEMM1: h1f8[N,128](fp8 e4m3) = x @ W1, fused f32 a_s1/a_d1 epilogue -------
// Also zeroes deg_s and pooled/cnt (grid-stride) so no memsets are needed.
__global__ __launch_bounds__(256) void k_gemm1(const float* __restrict__ x,
                                               const float* __restrict__ W1,
                                               const float* __restrict__ atts1,
                                               const float* __restrict__ attd1,
                                               int* __restrict__ h1f8,
                                               float* __restrict__ a_s, float* __restrict__ a_d,
                                               int* __restrict__ deg_s, int M8,
                                               float* __restrict__ poolcnt,
                                               int N) {
  __shared__ float Ws[64*128];
  __shared__ float xs[32*132];
  int t = threadIdx.x;
  int gid = blockIdx.x*256 + t;
  for (int z = gid; z < M8; z += gridDim.x*256) deg_s[z] = 0;
  if (gid < 1408) poolcnt[gid] = 0.f;
  int n0 = blockIdx.x * 32;
  const float4* W4 = (const float4*)W1;
  const float4* x4 = (const float4*)x;
  float4* Ws4 = (float4*)Ws;
  int cg = t & 31;
  int ng = t >> 5;
  float acc[4][4] = {};
  for (int p = 0; p < 2; ++p) {
    for (int i = 0; i < 8; ++i) {
      int idx = t + i*256;
      Ws4[idx] = W4[p*2048 + idx];
    }
    if (p == 0) {
      for (int i = 0; i < 4; ++i) {
        int idx = t + i*256;
        int row = idx >> 5, c4 = idx & 31;
        int nrow = n0 + row; if (nrow >= N) nrow = N - 1;
        float4 v = x4[(size_t)nrow*32 + c4];
        float* dst = &xs[row*132 + c4*4];
        dst[0] = v.x; dst[1] = v.y; dst[2] = v.z; dst[3] = v.w;
      }
    }
    __syncthreads();
    #pragma unroll 4
    for (int k = 0; k < 64; ++k) {
      float4 wv = Ws4[k*32 + cg];
      int kk = p*64 + k;
      float xv0 = xs[(ng*4+0)*132 + kk];
      float xv1 = xs[(ng*4+1)*132 + kk];
      float xv2 = xs[(ng*4+2)*132 + kk];
      float xv3 = xs[(ng*4+3)*132 + kk];
      acc[0][0] += xv0*wv.x; acc[0][1] += xv0*wv.y; acc[0][2] += xv0*wv.z; acc[0][3] += xv0*wv.w;
      acc[1][0] += xv1*wv.x; acc[1][1] += xv1*wv.y; acc[1][2] += xv1*wv.z; acc[1][3] += xv1*wv.w;
      acc[2][0] += xv2*wv.x; acc[2][1] += xv2*wv.y; acc[2][2] += xv2*wv.z; acc[2][3] += xv2*wv.w;
      acc[3][0] += xv3*wv.x; acc[3][1] += xv3*wv.y; acc[3][2] += xv3*wv.z; acc[3][3] += xv3*wv.w;
    }
    __syncthreads();
  }
  float4 as4 = ((const float4*)atts1)[cg];
  float4 ad4 = ((const float4*)attd1)[cg];
  int head = cg >> 3;
  #pragma unroll
  for (int i = 0; i < 4; ++i) {
    int n = n0 + ng*4 + i;
    if (n < N) {
      float4 o = make_float4(acc[i][0], acc[i][1], acc[i][2], acc[i][3]);
      int pk = __builtin_amdgcn_cvt_pk_fp8_f32(o.x, o.y, 0, false);
      pk = __builtin_amdgcn_cvt_pk_fp8_f32(o.z, o.w, pk, true);
      h1f8[(size_t)n*32 + cg] = pk;
      float ps = o.x*as4.x + o.y*as4.y + o.z*as4.z + o.w*as4.w;
      float pd = o.x*ad4.x + o.y*ad4.y + o.z*ad4.z + o.w*ad4.w;
      #pragma unroll
      for (int off = 4; off > 0; off >>= 1) {
        ps += __shfl_xor(ps, off, 8);
        pd += __shfl_xor(pd, off, 8);
      }
      if ((cg & 7) == 0) {
        a_s[n*4 + head] = ps;
        a_d[n*4 + head] = pd;
      }
    }
  }
}

// -------- CSR build, XCD-sharded (shard = blockIdx & 7 heuristic) --------
__global__ __launch_bounds__(256) void k_hist_sh(const int* __restrict__ ei, int E, int Etot,
                                                 int N, int* __restrict__ deg_s) {
  int e = blockIdx.x*256 + threadIdx.x;
  if (e >= Etot) return;
  int s = blockIdx.x & 7;
  int dst = (e < E) ? ei[E + e] : (e - E);
  atomicAdd(&deg_s[s*N + dst], 1);
}

// vectorized scan: 1024 thr, 4 ints/thread -> 4096 elems/block; exclusive out
__global__ __launch_bounds__(1024) void k_scan1v(const int* __restrict__ vin,
    int* __restrict__ vout, int* __restrict__ bsums, int M) {
  __shared__ int wsum[16];
  int t = threadIdx.x;
  int lane = t & 63, wave = t >> 6;
  size_t base = (size_t)blockIdx.x*4096 + (size_t)t*4;
  int4 v = make_int4(0,0,0,0);
  if (base + 3 < (size_t)M) {
    v = *(const int4*)(vin + base);
  } else {
    if (base+0 < (size_t)M) v.x = vin[base+0];
    if (base+1 < (size_t)M) v.y = vin[base+1];
    if (base+2 < (size_t)M) v.z = vin[base+2];
    if (base+3 < (size_t)M) v.w = vin[base+3];
  }
  int s0 = v.x, s1 = s0 + v.y, s2 = s1 + v.z, tot = s2 + v.w;
  int inc = tot;
  #pragma unroll
  for (int off = 1; off < 64; off <<= 1) {
    int u = __shfl_up(inc, off, 64);
    if (lane >= off) inc += u;
  }
  if (lane == 63) wsum[wave] = inc;
  __syncthreads();
  if (t < 16) {
    int w = wsum[t];
    int iw = w;
    #pragma unroll
    for (int off = 1; off < 16; off <<= 1) {
      int u = __shfl_up(iw, off, 16);
      if (t >= off) iw += u;
    }
    wsum[t] = iw - w;
    if (t == 15) bsums[blockIdx.x] = iw;
  }
  __syncthreads();
  int offb = wsum[wave] + (inc - tot);
  int4 o = make_int4(offb, offb + s0, offb + s1, offb + s2);
  if (base + 3 < (size_t)M) {
    *(int4*)(vout + base) = o;
  } else {
    if (base+0 < (size_t)M) vout[base+0] = o.x;
    if (base+1 < (size_t)M) vout[base+1] = o.y;
    if (base+2 < (size_t)M) vout[base+2] = o.z;
    if (base+3 < (size_t)M) vout[base+3] = o.w;
  }
}

// scan3A with INLINE scan of bsums (nb <= 256): SP += offset, cursor = SP, SP[M]=total
__global__ __launch_bounds__(256) void k_scan3A(int* __restrict__ SP,
    int* __restrict__ cursor, const int* __restrict__ bsums, int nb, int M, int total) {
  __shared__ int sc[256];
  int t = threadIdx.x;
  sc[t] = (t < nb) ? bsums[t] : 0;
  __syncthreads();
  for (int off = 1; off < 256; off <<= 1) {
    int v = (t >= off) ? sc[t - off] : 0;
    __syncthreads();
    sc[t] += v;
    __syncthreads();
  }
  int i = blockIdx.x*256 + t;
  if (i < M) {
    int blk = i >> 12;
    int add = (blk == 0) ? 0 : sc[blk - 1];
    int r = SP[i] + add;
    SP[i] = r;
    cursor[i] = r;
  }
  if (i == 0) SP[M] = total;
}

__global__ __launch_bounds__(256) void k_scatter_sh(const int* __restrict__ ei, int E, int Etot,
    int N, int* __restrict__ cursor, int* __restrict__ srcs_sh) {
  int e = blockIdx.x*256 + threadIdx.x;
  if (e >= Etot) return;
  int s = blockIdx.x & 7;
  int src, dst;
  if (e < E) { src = ei[e]; dst = ei[E + e]; } else { src = e - E; dst = src; }
  int pos = atomicAdd(&cursor[s*N + dst], 1);
  srcs_sh[pos] = src;
}

// compact: shard-major -> dst-major srcs; also computes rowptr[dst], per-edge
// ex1 (4 heads, f32) and per-dst denom1[4]. 8 lanes per dst.
__global__ __launch_bounds__(256) void k_compact(const int* __restrict__ SP,
    const int* __restrict__ srcs_sh, const float* __restrict__ a_s,
    const float* __restrict__ a_d, int* __restrict__ srcs,
    float* __restrict__ ex1, float* __restrict__ denom1,
    int* __restrict__ rowptr, int N, int Etot) {
  int tid = blockIdx.x*256 + threadIdx.x;
  if (tid == 0) rowptr[N] = Etot;
  int dst = tid >> 3;
  if (dst >= N) return;
  int s = tid & 7;
  int shbase = SP[s*N];
  int bg = SP[s*N + dst];
  int cnt = SP[s*N + dst + 1] - bg;
  int t_s = bg - shbase;
  int rsum = t_s;
  rsum += __shfl_xor(rsum, 1, 8);
  rsum += __shfl_xor(rsum, 2, 8);
  rsum += __shfl_xor(rsum, 4, 8);
  int incl = cnt;
  #pragma unroll
  for (int d = 1; d < 8; d <<= 1) {
    int o = __shfl_up(incl, d, 8);
    if (s >= d) incl += o;
  }
  int base = rsum + (incl - cnt);
  if (s == 0) rowptr[dst] = rsum;
  float4 ad4 = ((const float4*)a_d)[dst];
  float4 dsum = make_float4(0.f, 0.f, 0.f, 0.f);
  for (int k = 0; k < cnt; ++k) {
    int sv = srcs_sh[bg + k];
    srcs[base + k] = sv;
    float4 as4 = ((const float4*)a_s)[sv];
    float4 w;
    w.x = __expf(LRELU(as4.x + ad4.x));
    w.y = __expf(LRELU(as4.y + ad4.y));
    w.z = __expf(LRELU(as4.z + ad4.z));
    w.w = __expf(LRELU(as4.w + ad4.w));
    ((float4*)ex1)[base + k] = w;
    dsum.x += w.x; dsum.y += w.y; dsum.z += w.z; dsum.w += w.w;
  }
  #pragma unroll
  for (int d = 1; d < 8; d <<= 1) {
    dsum.x += __shfl_xor(dsum.x, d, 8);
    dsum.y += __shfl_xor(dsum.y, d, 8);
    dsum.z += __shfl_xor(dsum.z, d, 8);
    dsum.w += __shfl_xor(dsum.w, d, 8);
  }
  if (s == 0) ((float4*)denom1)[dst] = dsum;
}

// -------- layer-1 aggregation (fp8 gather, precomputed weights) + fused GEMM2 --------
__global__ __launch_bounds__(256) void k_agg1g2(const int* __restrict__ rowptr,
    const int* __restrict__ srcs, const float* __restrict__ ex1,
    const float* __restrict__ denom1, const int* __restrict__ h1f8,
    const float* __restrict__ b1, const float* __restrict__ W2,
    const float* __restrict__ atts2, const float* __restrict__ attd2,
    float* __restrict__ g, float* __restrict__ a_s2, float* __restrict__ a_d2,
    int N) {
  __shared__ float W2t[1280];   // W2t[c*128 + k] = W2[k*10 + c]
  __shared__ float att2s[20];
  int t = threadIdx.x;
  for (int f = t; f < 1280; f += 256) {
    int c = f >> 7, k = f & 127;
    W2t[f] = W2[k*10 + c];
  }
  if (t < 20) att2s[t] = (t < 10) ? atts2[t] : attd2[t - 10];
  __syncthreads();

  int dst = (blockIdx.x*256 + t) >> 5;
  if (dst >= N) return;
  int l = t & 31;
  int beg = rowptr[dst], end = rowptr[dst+1];
  int head = l >> 3;
  float4 acc = make_float4(0.f, 0.f, 0.f, 0.f);
  int j = beg;
  for (; j + 4 <= end; j += 4) {
    int s0 = srcs[j], s1 = srcs[j+1], s2 = srcs[j+2], s3 = srcs[j+3];
    float w0 = ex1[(size_t)j*4 + head];
    float w1 = ex1[(size_t)(j+1)*4 + head];
    float w2 = ex1[(size_t)(j+2)*4 + head];
    float w3 = ex1[(size_t)(j+3)*4 + head];
    int u0 = h1f8[(size_t)s0*32 + l];
    int u1 = h1f8[(size_t)s1*32 + l];
    int u2 = h1f8[(size_t)s2*32 + l];
    int u3 = h1f8[(size_t)s3*32 + l];
    v2f lo0 = __builtin_amdgcn_cvt_pk_f32_fp8(u0, false);
    v2f hi0 = __builtin_amdgcn_cvt_pk_f32_fp8(u0, true);
    v2f lo1 = __builtin_amdgcn_cvt_pk_f32_fp8(u1, false);
    v2f hi1 = __builtin_amdgcn_cvt_pk_f32_fp8(u1, true);
    v2f lo2 = __builtin_amdgcn_cvt_pk_f32_fp8(u2, false);
    v2f hi2 = __builtin_amdgcn_cvt_pk_f32_fp8(u2, true);
    v2f lo3 = __builtin_amdgcn_cvt_pk_f32_fp8(u3, false);
    v2f hi3 = __builtin_amdgcn_cvt_pk_f32_fp8(u3, true);
    acc.x += w0*lo0.x + w1*lo1.x + w2*lo2.x + w3*lo3.x;
    acc.y += w0*lo0.y + w1*lo1.y + w2*lo2.y + w3*lo3.y;
    acc.z += w0*hi0.x + w1*hi1.x + w2*hi2.x + w3*hi3.x;
    acc.w += w0*hi0.y + w1*hi1.y + w2*hi2.y + w3*hi3.y;
  }
  for (; j < end; ++j) {
    int s = srcs[j];
    float w = ex1[(size_t)j*4 + head];
    int u = h1f8[(size_t)s*32 + l];
    v2f lo = __builtin_amdgcn_cvt_pk_f32_fp8(u, false);
    v2f hi = __builtin_amdgcn_cvt_pk_f32_fp8(u, true);
    acc.x += w*lo.x; acc.y += w*lo.y; acc.z += w*hi.x; acc.w += w*hi.y;
  }
  float inv = 1.0f / (denom1[dst*4 + head] + 1e-16f);
  float4 b14 = ((const float4*)b1)[l];
  float h0 = acc.x*inv + b14.x; h0 = h0 > 0.f ? h0 : __expf(h0) - 1.0f;
  float h1v = acc.y*inv + b14.y; h1v = h1v > 0.f ? h1v : __expf(h1v) - 1.0f;
  float h2v = acc.z*inv + b14.z; h2v = h2v > 0.f ? h2v : __expf(h2v) - 1.0f;
  float h3v = acc.w*inv + b14.w; h3v = h3v > 0.f ? h3v : __expf(h3v) - 1.0f;
  const float4* W2t4 = (const float4*)W2t;
  float p[10];
  #pragma unroll
  for (int c = 0; c < 10; ++c) {
    float4 wv = W2t4[c*32 + l];
    p[c] = h0*wv.x + h1v*wv.y + h2v*wv.z + h3v*wv.w;
  }
  #pragma unroll
  for (int off = 16; off > 0; off >>= 1) {
    #pragma unroll
    for (int c = 0; c < 10; ++c)
      p[c] += __shfl_xor(p[c], off, 32);
  }
  if (l < 10) {
    float val = p[0];
    #pragma unroll
    for (int c = 1; c < 10; ++c) val = (l == c) ? p[c] : val;
    g[(size_t)dst*16 + l] = val;          // 64B-padded rows
  }
  if (l == 0) {
    float as = 0.f, adv = 0.f;
    #pragma unroll
    for (int c = 0; c < 10; ++c) {
      as  += p[c]*att2s[c];
      adv += p[c]*att2s[10 + c];
    }
    a_s2[dst] = as;
    a_d2[dst] = adv;
  }
}

// -------- layer-2 aggregation fused with bias/elu/pool: 16 lanes/dst --------
__global__ __launch_bounds__(256) void k_agg2f(const int* __restrict__ rowptr,
    const int* __restrict__ srcs, const float* __restrict__ a_s,
    const float* __restrict__ a_d, const float* __restrict__ g,
    const float* __restrict__ b2, const int* __restrict__ batch,
    float* __restrict__ pooled, float* __restrict__ cnt, int N) {
  __shared__ float lp[4*10];
  __shared__ float lc[4];
  __shared__ int b0s;
  int t = threadIdx.x;
  int dst = (blockIdx.x*256 + t) >> 4;
  int l = t & 15;
  if (t < 40) lp[t] = 0.f;
  if (t < 4) lc[t] = 0.f;
  if (t == 0) {
    int d0 = (blockIdx.x*256) >> 4;
    if (d0 > N - 1) d0 = N - 1;
    b0s = batch[d0];
  }
  __syncthreads();
  int b0 = b0s;
  bool valid = (dst < N);
  float o = 0.f;
  int b = 0;
  if (valid) {
    int beg = rowptr[dst], end = rowptr[dst+1];
    float ad = a_d[dst];
    float denom = 0.f;
    float acc = 0.f;
    bool act = (l < 10);
    int li = act ? l : 0;
    int j = beg;
    for (; j + 4 <= end; j += 4) {
      int s0 = srcs[j], s1 = srcs[j+1], s2 = srcs[j+2], s3 = srcs[j+3];
      float w0 = __expf(LRELU(a_s[s0] + ad));
      float w1 = __expf(LRELU(a_s[s1] + ad));
      float w2 = __expf(LRELU(a_s[s2] + ad));
      float w3 = __expf(LRELU(a_s[s3] + ad));
      float g0 = g[(size_t)s0*16 + li];
      float g1 = g[(size_t)s1*16 + li];
      float g2 = g[(size_t)s2*16 + li];
      float g3 = g[(size_t)s3*16 + li];
      denom += (w0 + w1) + (w2 + w3);
      acc += w0*g0 + w1*g1 + w2*g2 + w3*g3;
    }
    for (; j < end; ++j) {
      int s = srcs[j];
      float w = __expf(LRELU(a_s[s] + ad));
      float gv = g[(size_t)s*16 + li];
      denom += w;
      acc += w*gv;
    }
    b = batch[dst];
    if (l < 10) {
      o = acc / (denom + 1e-16f) + b2[l];
      o = o > 0.f ? o : __expf(o) - 1.0f;
    }
  }
  if (valid) {
    int bl = b - b0;
    if (l < 10) {
      if (bl < 4) atomicAdd(&lp[bl*10 + l], o);
      else atomicAdd(&pooled[b*10 + l], o);
    }
    if (l == 0) {
      if (bl < 4) atomicAdd(&lc[bl], 1.0f);
      else atomicAdd(&cnt[b], 1.0f);
    }
  }
  __syncthreads();
  if (t < 40) {
    int bl = t / 10, c = t - bl*10;
    int bb = b0 + bl;
    if (bb < 128 && lp[t] != 0.f) atomicAdd(&pooled[bb*10 + c], lp[t]);
  }
  if (t < 4) {
    int bb = b0 + t;
    if (bb < 128 && lc[t] != 0.f) atomicAdd(&cnt[bb], lc[t]);
  }
}

__global__ __launch_bounds__(128) void k_softmax(const float* __restrict__ pooled,
    const float* __restrict__ cnt, float* __restrict__ out) {
  int t = threadIdx.x;
  float inv = 1.0f / fmaxf(cnt[t], 1.0f);
  float v[10], m = -1e30f;
  #pragma unroll
  for (int c = 0; c < 10; ++c) { v[c] = pooled[t*10 + c] * inv; m = fmaxf(m, v[c]); }
  float s = 0.f;
  #pragma unroll
  for (int c = 0; c < 10; ++c) s += __expf(v[c] - m);
  float ls = logf(s) + m;
  #pragma unroll
  for (int c = 0; c < 10; ++c) out[t*10 + c] = v[c] - ls;
}

extern "C" void kernel_launch(void* const* d_in, const int* in_sizes, int n_in,
                              void* d_out, int out_size, void* d_ws, size_t ws_size,
                              hipStream_t stream) {
  const float* x     = (const float*)d_in[0];
  const float* W1    = (const float*)d_in[1];
  const float* atts1 = (const float*)d_in[2];
  const float* attd1 = (const float*)d_in[3];
  const float* b1    = (const float*)d_in[4];
  const float* W2    = (const float*)d_in[5];
  const float* atts2 = (const float*)d_in[6];
  const float* attd2 = (const float*)d_in[7];
  const float* b2    = (const float*)d_in[8];
  const int*   ei    = (const int*)d_in[9];
  const int*   batch = (const int*)d_in[10];
  int N = in_sizes[10];
  int E = in_sizes[9] / 2;
  int Etot = E + N;
  int M8 = 8 * N;

  char* base = (char*)d_ws;
  size_t off = 0;
  auto allocB = [&](size_t bytes) { void* p = (void*)(base + off); off += (bytes + 63) & ~size_t(63); return p; };

  int*   h1f8   = (int*)allocB((size_t)N*32*sizeof(int));
  float* a_s1   = (float*)allocB((size_t)N*4*sizeof(float));
  float* a_d1   = (float*)allocB((size_t)N*4*sizeof(float));
  float* ex1    = (float*)allocB((size_t)Etot*4*sizeof(float));
  float* denom1 = (float*)allocB((size_t)N*4*sizeof(float));
  float* g      = (float*)allocB((size_t)N*16*sizeof(float));
  float* a_s2   = (float*)allocB((size_t)N*sizeof(float));
  float* a_d2   = (float*)allocB((size_t)N*sizeof(float));
  float* poolcnt= (float*)allocB(1408*sizeof(float));   // pooled[1280] + cnt[128]
  int* deg_s  = (int*)allocB((size_t)M8*sizeof(int));
  int* SP     = (int*)allocB((size_t)(M8+1)*sizeof(int));
  int* cursor = (int*)allocB((size_t)M8*sizeof(int));
  int* rowptr = (int*)allocB((size_t)(N+1)*sizeof(int));
  int* bsumsA = (int*)allocB(1024*sizeof(int));
  int* srcs_sh= (int*)allocB((size_t)Etot*sizeof(int));
  int* srcs   = (int*)allocB((size_t)Etot*sizeof(int));

  float* pooled = poolcnt;
  float* cnt    = poolcnt + 1280;
  int nbA = (M8 + 4095) / 4096;   // 196 for N=100k (<=256 required by k_scan3A)

  k_gemm1<<<dim3((N + 31)/32), dim3(256), 0, stream>>>(x, W1, atts1, attd1, h1f8,
                                                       a_s1, a_d1, deg_s, M8, poolcnt, N);
  k_hist_sh<<<dim3((Etot + 255)/256), dim3(256), 0, stream>>>(ei, E, Etot, N, deg_s);
  k_scan1v<<<dim3(nbA), dim3(1024), 0, stream>>>(deg_s, SP, bsumsA, M8);
  k_scan3A<<<dim3((M8 + 255)/256), dim3(256), 0, stream>>>(SP, cursor, bsumsA, nbA, M8, Etot);
  k_scatter_sh<<<dim3((Etot + 255)/256), dim3(256), 0, stream>>>(ei, E, Etot, N, cursor, srcs_sh);
  k_compact<<<dim3((N*8 + 255)/256), dim3(256), 0, stream>>>(SP, srcs_sh, a_s1, a_d1,
                                                             srcs, ex1, denom1, rowptr, N, Etot);
  k_agg1g2<<<dim3((N*32 + 255)/256), dim3(256), 0, stream>>>(rowptr, srcs, ex1, denom1, h1f8,
                                                             b1, W2, atts2, attd2,
                                                             g, a_s2, a_d2, N);
  k_agg2f<<<dim3((N*16 + 255)/256), dim3(256), 0, stream>>>(rowptr, srcs, a_s2, a_d2, g,
                                                            b2, batch, pooled, cnt, N);
  k_softmax<<<dim3(1), dim3(128), 0, stream>>>(pooled, cnt, (float*)d_out);
}

// Round 9
// 417.557 us; speedup vs baseline: 9.7851x; 1.0650x over previous
//
#include <hip/hip_runtime.h>
#include <cstdint>
#include <cstddef>

#define LRELU(x) fmaxf((x), 0.2f*(x))

typedef float v2f __attribute__((ext_vector_type(2)));

// ------- GEMM1: h1f8[N,128](fp8 e4m3) = x @ W1, fused f32 a_s1/a_d1 epilogue -------
// Also zeroes deg_s and pooled/cnt (grid-stride) so no memsets are needed.
__global__ __launch_bounds__(256) void k_gemm1(const float* __restrict__ x,
                                               const float* __restrict__ W1,
                                               const float* __restrict__ atts1,
                                               const float* __restrict__ attd1,
                                               int* __restrict__ h1f8,
                                               float* __restrict__ a_s, float* __restrict__ a_d,
                                               int* __restrict__ deg_s, int M8,
                                               float* __restrict__ poolcnt,
                                               int N) {
  __shared__ float Ws[64*128];
  __shared__ float xs[32*132];
  int t = threadIdx.x;
  int gid = blockIdx.x*256 + t;
  for (int z = gid; z < M8; z += gridDim.x*256) deg_s[z] = 0;
  if (gid < 1408) poolcnt[gid] = 0.f;
  int n0 = blockIdx.x * 32;
  const float4* W4 = (const float4*)W1;
  const float4* x4 = (const float4*)x;
  float4* Ws4 = (float4*)Ws;
  int cg = t & 31;
  int ng = t >> 5;
  float acc[4][4] = {};
  for (int p = 0; p < 2; ++p) {
    for (int i = 0; i < 8; ++i) {
      int idx = t + i*256;
      Ws4[idx] = W4[p*2048 + idx];
    }
    if (p == 0) {
      for (int i = 0; i < 4; ++i) {
        int idx = t + i*256;
        int row = idx >> 5, c4 = idx & 31;
        int nrow = n0 + row; if (nrow >= N) nrow = N - 1;
        float4 v = x4[(size_t)nrow*32 + c4];
        float* dst = &xs[row*132 + c4*4];
        dst[0] = v.x; dst[1] = v.y; dst[2] = v.z; dst[3] = v.w;
      }
    }
    __syncthreads();
    #pragma unroll 4
    for (int k = 0; k < 64; ++k) {
      float4 wv = Ws4[k*32 + cg];
      int kk = p*64 + k;
      float xv0 = xs[(ng*4+0)*132 + kk];
      float xv1 = xs[(ng*4+1)*132 + kk];
      float xv2 = xs[(ng*4+2)*132 + kk];
      float xv3 = xs[(ng*4+3)*132 + kk];
      acc[0][0] += xv0*wv.x; acc[0][1] += xv0*wv.y; acc[0][2] += xv0*wv.z; acc[0][3] += xv0*wv.w;
      acc[1][0] += xv1*wv.x; acc[1][1] += xv1*wv.y; acc[1][2] += xv1*wv.z; acc[1][3] += xv1*wv.w;
      acc[2][0] += xv2*wv.x; acc[2][1] += xv2*wv.y; acc[2][2] += xv2*wv.z; acc[2][3] += xv2*wv.w;
      acc[3][0] += xv3*wv.x; acc[3][1] += xv3*wv.y; acc[3][2] += xv3*wv.z; acc[3][3] += xv3*wv.w;
    }
    __syncthreads();
  }
  float4 as4 = ((const float4*)atts1)[cg];
  float4 ad4 = ((const float4*)attd1)[cg];
  int head = cg >> 3;
  #pragma unroll
  for (int i = 0; i < 4; ++i) {
    int n = n0 + ng*4 + i;
    if (n < N) {
      float4 o = make_float4(acc[i][0], acc[i][1], acc[i][2], acc[i][3]);
      int pk = __builtin_amdgcn_cvt_pk_fp8_f32(o.x, o.y, 0, false);
      pk = __builtin_amdgcn_cvt_pk_fp8_f32(o.z, o.w, pk, true);
      h1f8[(size_t)n*32 + cg] = pk;
      float ps = o.x*as4.x + o.y*as4.y + o.z*as4.z + o.w*as4.w;
      float pd = o.x*ad4.x + o.y*ad4.y + o.z*ad4.z + o.w*ad4.w;
      #pragma unroll
      for (int off = 4; off > 0; off >>= 1) {
        ps += __shfl_xor(ps, off, 8);
        pd += __shfl_xor(pd, off, 8);
      }
      if ((cg & 7) == 0) {
        a_s[n*4 + head] = ps;
        a_d[n*4 + head] = pd;
      }
    }
  }
}

// -------- CSR build, XCD-sharded (shard = blockIdx & 7 heuristic) --------
__global__ __launch_bounds__(256) void k_hist_sh(const int* __restrict__ ei, int E, int Etot,
                                                 int N, int* __restrict__ deg_s) {
  int e = blockIdx.x*256 + threadIdx.x;
  if (e >= Etot) return;
  int s = blockIdx.x & 7;
  int dst = (e < E) ? ei[E + e] : (e - E);
  atomicAdd(&deg_s[s*N + dst], 1);
}

// vectorized scan: 1024 thr, 4 ints/thread -> 4096 elems/block; exclusive out
__global__ __launch_bounds__(1024) void k_scan1v(const int* __restrict__ vin,
    int* __restrict__ vout, int* __restrict__ bsums, int M) {
  __shared__ int wsum[16];
  int t = threadIdx.x;
  int lane = t & 63, wave = t >> 6;
  size_t base = (size_t)blockIdx.x*4096 + (size_t)t*4;
  int4 v = make_int4(0,0,0,0);
  if (base + 3 < (size_t)M) {
    v = *(const int4*)(vin + base);
  } else {
    if (base+0 < (size_t)M) v.x = vin[base+0];
    if (base+1 < (size_t)M) v.y = vin[base+1];
    if (base+2 < (size_t)M) v.z = vin[base+2];
    if (base+3 < (size_t)M) v.w = vin[base+3];
  }
  int s0 = v.x, s1 = s0 + v.y, s2 = s1 + v.z, tot = s2 + v.w;
  int inc = tot;
  #pragma unroll
  for (int off = 1; off < 64; off <<= 1) {
    int u = __shfl_up(inc, off, 64);
    if (lane >= off) inc += u;
  }
  if (lane == 63) wsum[wave] = inc;
  __syncthreads();
  if (t < 16) {
    int w = wsum[t];
    int iw = w;
    #pragma unroll
    for (int off = 1; off < 16; off <<= 1) {
      int u = __shfl_up(iw, off, 16);
      if (t >= off) iw += u;
    }
    wsum[t] = iw - w;
    if (t == 15) bsums[blockIdx.x] = iw;
  }
  __syncthreads();
  int offb = wsum[wave] + (inc - tot);
  int4 o = make_int4(offb, offb + s0, offb + s1, offb + s2);
  if (base + 3 < (size_t)M) {
    *(int4*)(vout + base) = o;
  } else {
    if (base+0 < (size_t)M) vout[base+0] = o.x;
    if (base+1 < (size_t)M) vout[base+1] = o.y;
    if (base+2 < (size_t)M) vout[base+2] = o.z;
    if (base+3 < (size_t)M) vout[base+3] = o.w;
  }
}

// scan3A with INLINE scan of bsums (nb <= 256): SP += offset, cursor = SP, SP[M]=total
__global__ __launch_bounds__(256) void k_scan3A(int* __restrict__ SP,
    int* __restrict__ cursor, const int* __restrict__ bsums, int nb, int M, int total) {
  __shared__ int sc[256];
  int t = threadIdx.x;
  sc[t] = (t < nb) ? bsums[t] : 0;
  __syncthreads();
  for (int off = 1; off < 256; off <<= 1) {
    int v = (t >= off) ? sc[t - off] : 0;
    __syncthreads();
    sc[t] += v;
    __syncthreads();
  }
  int i = blockIdx.x*256 + t;
  if (i < M) {
    int blk = i >> 12;
    int add = (blk == 0) ? 0 : sc[blk - 1];
    int r = SP[i] + add;
    SP[i] = r;
    cursor[i] = r;
  }
  if (i == 0) SP[M] = total;
}

__global__ __launch_bounds__(256) void k_scatter_sh(const int* __restrict__ ei, int E, int Etot,
    int N, int* __restrict__ cursor, int* __restrict__ srcs_sh) {
  int e = blockIdx.x*256 + threadIdx.x;
  if (e >= Etot) return;
  int s = blockIdx.x & 7;
  int src, dst;
  if (e < E) { src = ei[e]; dst = ei[E + e]; } else { src = e - E; dst = src; }
  int pos = atomicAdd(&cursor[s*N + dst], 1);
  srcs_sh[pos] = src;
}

// compact: pure shard-major -> dst-major copy + rowptr (8 lanes per dst)
__global__ __launch_bounds__(256) void k_compact(const int* __restrict__ SP,
    const int* __restrict__ srcs_sh, int* __restrict__ srcs,
    int* __restrict__ rowptr, int N, int Etot) {
  int tid = blockIdx.x*256 + threadIdx.x;
  if (tid == 0) rowptr[N] = Etot;
  int dst = tid >> 3;
  if (dst >= N) return;
  int s = tid & 7;
  int shbase = SP[s*N];
  int bg = SP[s*N + dst];
  int cnt = SP[s*N + dst + 1] - bg;
  int t_s = bg - shbase;
  int rsum = t_s;
  rsum += __shfl_xor(rsum, 1, 8);
  rsum += __shfl_xor(rsum, 2, 8);
  rsum += __shfl_xor(rsum, 4, 8);
  int incl = cnt;
  #pragma unroll
  for (int d = 1; d < 8; d <<= 1) {
    int o = __shfl_up(incl, d, 8);
    if (s >= d) incl += o;
  }
  int base = rsum + (incl - cnt);
  if (s == 0) rowptr[dst] = rsum;
  for (int k = 0; k < cnt; ++k) srcs[base + k] = srcs_sh[bg + k];
}

// -------- layer-1 aggregation (fp8 gather, lane-split exp) + fused GEMM2 --------
// 32 lanes/dst. Batch of 8 edges: lane (e*4+h) computes w for edge e, head h;
// consumers get (s_e, w_e) via shfl. Denom accumulated in-loop.
__global__ __launch_bounds__(256) void k_agg1g2(const int* __restrict__ rowptr,
    const int* __restrict__ srcs, const float* __restrict__ a_s,
    const float* __restrict__ a_d, const int* __restrict__ h1f8,
    const float* __restrict__ b1, const float* __restrict__ W2,
    const float* __restrict__ atts2, const float* __restrict__ attd2,
    float* __restrict__ g, float* __restrict__ a_s2, float* __restrict__ a_d2,
    int N) {
  __shared__ float W2t[1280];   // W2t[c*128 + k] = W2[k*10 + c]
  __shared__ float att2s[20];
  int t = threadIdx.x;
  for (int f = t; f < 1280; f += 256) {
    int c = f >> 7, k = f & 127;
    W2t[f] = W2[k*10 + c];
  }
  if (t < 20) att2s[t] = (t < 10) ? atts2[t] : attd2[t - 10];
  __syncthreads();

  int dst = (blockIdx.x*256 + t) >> 5;
  if (dst >= N) return;
  int l = t & 31;
  int head = l >> 3;
  int eh = l & 3;    // head this lane computes exp for
  int ee = l >> 2;   // edge slot this lane computes exp for (0..7)
  int beg = rowptr[dst], end = rowptr[dst+1];
  float4 ad4 = ((const float4*)a_d)[dst];
  float adh = (eh==0) ? ad4.x : (eh==1) ? ad4.y : (eh==2) ? ad4.z : ad4.w;
  float denom = 0.f;
  float4 acc = make_float4(0.f, 0.f, 0.f, 0.f);
  for (int j = beg; j < end; j += 8) {
    int rm = end - j - 1;                 // >= 0
    int je = j + (ee < rm ? ee : rm);     // clamped (valid) edge index
    int se = srcs[je];
    float4 as4 = ((const float4*)a_s)[se];
    float ash = (eh==0) ? as4.x : (eh==1) ? as4.y : (eh==2) ? as4.z : as4.w;
    float w = __expf(LRELU(ash + adh));
    if (ee > rm) w = 0.f;                 // mask tail slots
    #pragma unroll
    for (int e = 0; e < 8; ++e) {
      int s_e   = __shfl(se, e*4, 32);
      float w_e = __shfl(w, e*4 + head, 32);
      int u = h1f8[(size_t)s_e*32 + l];
      v2f lo = __builtin_amdgcn_cvt_pk_f32_fp8(u, false);
      v2f hi = __builtin_amdgcn_cvt_pk_f32_fp8(u, true);
      acc.x += w_e*lo.x; acc.y += w_e*lo.y;
      acc.z += w_e*hi.x; acc.w += w_e*hi.y;
      denom += w_e;
    }
  }
  float inv = 1.0f / (denom + 1e-16f);
  float4 b14 = ((const float4*)b1)[l];
  float h0 = acc.x*inv + b14.x; h0 = h0 > 0.f ? h0 : __expf(h0) - 1.0f;
  float h1v = acc.y*inv + b14.y; h1v = h1v > 0.f ? h1v : __expf(h1v) - 1.0f;
  float h2v = acc.z*inv + b14.z; h2v = h2v > 0.f ? h2v : __expf(h2v) - 1.0f;
  float h3v = acc.w*inv + b14.w; h3v = h3v > 0.f ? h3v : __expf(h3v) - 1.0f;
  const float4* W2t4 = (const float4*)W2t;
  float p[10];
  #pragma unroll
  for (int c = 0; c < 10; ++c) {
    float4 wv = W2t4[c*32 + l];
    p[c] = h0*wv.x + h1v*wv.y + h2v*wv.z + h3v*wv.w;
  }
  #pragma unroll
  for (int off = 16; off > 0; off >>= 1) {
    #pragma unroll
    for (int c = 0; c < 10; ++c)
      p[c] += __shfl_xor(p[c], off, 32);
  }
  if (l < 10) {
    float val = p[0];
    #pragma unroll
    for (int c = 1; c < 10; ++c) val = (l == c) ? p[c] : val;
    g[(size_t)dst*16 + l] = val;          // 64B-padded rows
  }
  if (l == 0) {
    float as = 0.f, adv = 0.f;
    #pragma unroll
    for (int c = 0; c < 10; ++c) {
      as  += p[c]*att2s[c];
      adv += p[c]*att2s[10 + c];
    }
    a_s2[dst] = as;
    a_d2[dst] = adv;
  }
}

// -------- layer-2 aggregation, edges-across-lanes, fused bias/elu/pool --------
// 16 lanes/dst; lane l handles edges beg+l, beg+l+16, ... with 10 accumulators.
__global__ __launch_bounds__(256) void k_agg2f(const int* __restrict__ rowptr,
    const int* __restrict__ srcs, const float* __restrict__ a_s,
    const float* __restrict__ a_d, const float* __restrict__ g,
    const float* __restrict__ b2, const int* __restrict__ batch,
    float* __restrict__ pooled, float* __restrict__ cnt, int N) {
  __shared__ float lp[4*10];
  __shared__ float lc[4];
  __shared__ int b0s;
  int t = threadIdx.x;
  int dst = (blockIdx.x*256 + t) >> 4;
  int l = t & 15;
  if (t < 40) lp[t] = 0.f;
  if (t < 4) lc[t] = 0.f;
  if (t == 0) {
    int d0 = (blockIdx.x*256) >> 4;
    if (d0 > N - 1) d0 = N - 1;
    b0s = batch[d0];
  }
  __syncthreads();
  int b0 = b0s;
  bool valid = (dst < N);
  float o = 0.f;
  int b = 0;
  if (valid) {
    int beg = rowptr[dst], end = rowptr[dst+1];
    float ad = a_d[dst];
    float acc[10] = {};
    float denom = 0.f;
    const float4* g4 = (const float4*)g;
    for (int j = beg + l; j < end; j += 16) {
      int s = srcs[j];
      float w = __expf(LRELU(a_s[s] + ad));
      float4 ga = g4[(size_t)s*4 + 0];
      float4 gb = g4[(size_t)s*4 + 1];
      float4 gc = g4[(size_t)s*4 + 2];
      denom += w;
      acc[0] += w*ga.x; acc[1] += w*ga.y; acc[2] += w*ga.z; acc[3] += w*ga.w;
      acc[4] += w*gb.x; acc[5] += w*gb.y; acc[6] += w*gb.z; acc[7] += w*gb.w;
      acc[8] += w*gc.x; acc[9] += w*gc.y;
    }
    #pragma unroll
    for (int off = 8; off > 0; off >>= 1) {
      denom += __shfl_xor(denom, off, 16);
      #pragma unroll
      for (int c = 0; c < 10; ++c) acc[c] += __shfl_xor(acc[c], off, 16);
    }
    b = batch[dst];
    if (l < 10) {
      o = acc[l] / (denom + 1e-16f) + b2[l];
      o = o > 0.f ? o : __expf(o) - 1.0f;
    }
  }
  if (valid) {
    int bl = b - b0;
    if (l < 10) {
      if (bl < 4) atomicAdd(&lp[bl*10 + l], o);
      else atomicAdd(&pooled[b*10 + l], o);
    }
    if (l == 0) {
      if (bl < 4) atomicAdd(&lc[bl], 1.0f);
      else atomicAdd(&cnt[b], 1.0f);
    }
  }
  __syncthreads();
  if (t < 40) {
    int bl = t / 10, c = t - bl*10;
    int bb = b0 + bl;
    if (bb < 128 && lp[t] != 0.f) atomicAdd(&pooled[bb*10 + c], lp[t]);
  }
  if (t < 4) {
    int bb = b0 + t;
    if (bb < 128 && lc[t] != 0.f) atomicAdd(&cnt[bb], lc[t]);
  }
}

__global__ __launch_bounds__(128) void k_softmax(const float* __restrict__ pooled,
    const float* __restrict__ cnt, float* __restrict__ out) {
  int t = threadIdx.x;
  float inv = 1.0f / fmaxf(cnt[t], 1.0f);
  float v[10], m = -1e30f;
  #pragma unroll
  for (int c = 0; c < 10; ++c) { v[c] = pooled[t*10 + c] * inv; m = fmaxf(m, v[c]); }
  float s = 0.f;
  #pragma unroll
  for (int c = 0; c < 10; ++c) s += __expf(v[c] - m);
  float ls = logf(s) + m;
  #pragma unroll
  for (int c = 0; c < 10; ++c) out[t*10 + c] = v[c] - ls;
}

extern "C" void kernel_launch(void* const* d_in, const int* in_sizes, int n_in,
                              void* d_out, int out_size, void* d_ws, size_t ws_size,
                              hipStream_t stream) {
  const float* x     = (const float*)d_in[0];
  const float* W1    = (const float*)d_in[1];
  const float* atts1 = (const float*)d_in[2];
  const float* attd1 = (const float*)d_in[3];
  const float* b1    = (const float*)d_in[4];
  const float* W2    = (const float*)d_in[5];
  const float* atts2 = (const float*)d_in[6];
  const float* attd2 = (const float*)d_in[7];
  const float* b2    = (const float*)d_in[8];
  const int*   ei    = (const int*)d_in[9];
  const int*   batch = (const int*)d_in[10];
  int N = in_sizes[10];
  int E = in_sizes[9] / 2;
  int Etot = E + N;
  int M8 = 8 * N;

  char* base = (char*)d_ws;
  size_t off = 0;
  auto allocB = [&](size_t bytes) { void* p = (void*)(base + off); off += (bytes + 63) & ~size_t(63); return p; };

  int*   h1f8   = (int*)allocB((size_t)N*32*sizeof(int));
  float* a_s1   = (float*)allocB((size_t)N*4*sizeof(float));
  float* a_d1   = (float*)allocB((size_t)N*4*sizeof(float));
  float* g      = (float*)allocB((size_t)N*16*sizeof(float));
  float* a_s2   = (float*)allocB((size_t)N*sizeof(float));
  float* a_d2   = (float*)allocB((size_t)N*sizeof(float));
  float* poolcnt= (float*)allocB(1408*sizeof(float));   // pooled[1280] + cnt[128]
  int* deg_s  = (int*)allocB((size_t)M8*sizeof(int));
  int* SP     = (int*)allocB((size_t)(M8+1)*sizeof(int));
  int* cursor = (int*)allocB((size_t)M8*sizeof(int));
  int* rowptr = (int*)allocB((size_t)(N+1)*sizeof(int));
  int* bsumsA = (int*)allocB(1024*sizeof(int));
  int* srcs_sh= (int*)allocB((size_t)Etot*sizeof(int));
  int* srcs   = (int*)allocB((size_t)Etot*sizeof(int));

  float* pooled = poolcnt;
  float* cnt    = poolcnt + 1280;
  int nbA = (M8 + 4095) / 4096;   // 196 for N=100k (<=256 required by k_scan3A)

  k_gemm1<<<dim3((N + 31)/32), dim3(256), 0, stream>>>(x, W1, atts1, attd1, h1f8,
                                                       a_s1, a_d1, deg_s, M8, poolcnt, N);
  k_hist_sh<<<dim3((Etot + 255)/256), dim3(256), 0, stream>>>(ei, E, Etot, N, deg_s);
  k_scan1v<<<dim3(nbA), dim3(1024), 0, stream>>>(deg_s, SP, bsumsA, M8);
  k_scan3A<<<dim3((M8 + 255)/256), dim3(256), 0, stream>>>(SP, cursor, bsumsA, nbA, M8, Etot);
  k_scatter_sh<<<dim3((Etot + 255)/256), dim3(256), 0, stream>>>(ei, E, Etot, N, cursor, srcs_sh);
  k_compact<<<dim3((N*8 + 255)/256), dim3(256), 0, stream>>>(SP, srcs_sh, srcs, rowptr, N, Etot);
  k_agg1g2<<<dim3((N*32 + 255)/256), dim3(256), 0, stream>>>(rowptr, srcs, a_s1, a_d1, h1f8,
                                                             b1, W2, atts2, attd2,
                                                             g, a_s2, a_d2, N);
  k_agg2f<<<dim3((N*16 + 255)/256), dim3(256), 0, stream>>>(rowptr, srcs, a_s2, a_d2, g,
                                                            b2, batch, pooled, cnt, N);
  k_softmax<<<dim3(1), dim3(128), 0, stream>>>(pooled, cnt, (float*)d_out);
}

// Round 10
// 389.809 us; speedup vs baseline: 10.4816x; 1.0712x over previous
//
#include <hip/hip_runtime.h>
#include <cstdint>
#include <cstddef>

#define LRELU(x) fmaxf((x), 0.2f*(x))

typedef float v2f __attribute__((ext_vector_type(2)));
typedef __attribute__((ext_vector_type(8))) short short8;
typedef __attribute__((ext_vector_type(4))) float f32x4;

__device__ inline unsigned short f2bf(float f) {
  unsigned u = __float_as_uint(f);
  u += 0x8000u;
  return (unsigned short)(u >> 16);
}
__device__ inline float bflo(unsigned u) { return __uint_as_float(u << 16); }
__device__ inline float bfhi(unsigned u) { return __uint_as_float(u & 0xffff0000u); }

// ------- GEMM1 (MFMA bf16): h1f8[N,128](fp8) = x @ W1, fused a_s1/a_d1 -------
// 64 nodes/block (16/wave). W1^T staged as bf16 in LDS (stride 136 shorts);
// A-frags loaded from global; C transposed through reused LDS; epilogue packs
// fp8 + per-(node,head) attention dots (no shuffles). Also zeroes deg_s/poolcnt.
__global__ __launch_bounds__(256) void k_gemm1(const float* __restrict__ x,
                                               const float* __restrict__ W1,
                                               const float* __restrict__ atts1,
                                               const float* __restrict__ attd1,
                                               int* __restrict__ h1f8,
                                               float* __restrict__ a_s, float* __restrict__ a_d,
                                               int* __restrict__ deg_s, int M8,
                                               float* __restrict__ poolcnt,
                                               int N) {
  __shared__ short Wt[128*136];   // 34816 B; reused as f32 hs (4x16x132) after MFMA
  int t = threadIdx.x;
  int gid = blockIdx.x*256 + t;
  for (int z = gid; z < M8; z += gridDim.x*256) deg_s[z] = 0;
  if (gid < 1408) poolcnt[gid] = 0.f;

  // stage Wt[n][k] = bf16(W1[k][n]); coalesced 256B global reads per k step
  {
    int n = t & 127, half = t >> 7;
    for (int kk0 = 0; kk0 < 64; kk0 += 4) {
      short v0 = (short)f2bf(W1[(half*64 + kk0 + 0)*128 + n]);
      short v1 = (short)f2bf(W1[(half*64 + kk0 + 1)*128 + n]);
      short v2 = (short)f2bf(W1[(half*64 + kk0 + 2)*128 + n]);
      short v3 = (short)f2bf(W1[(half*64 + kk0 + 3)*128 + n]);
      *(short4*)(&Wt[n*136 + half*64 + kk0]) = make_short4(v0, v1, v2, v3);
    }
  }
  __syncthreads();

  int w = t >> 6, l = t & 63;
  int n0 = blockIdx.x*64 + w*16;
  int mrow = l & 15, q = l >> 4;
  int nrow = n0 + mrow; if (nrow >= N) nrow = N - 1;
  const float4* xrow = (const float4*)(x + (size_t)nrow*128);
  f32x4 acc[8];
  #pragma unroll
  for (int i = 0; i < 8; ++i) acc[i] = (f32x4){0.f, 0.f, 0.f, 0.f};
  #pragma unroll
  for (int kc = 0; kc < 4; ++kc) {
    float4 xa = xrow[kc*8 + q*2];
    float4 xb = xrow[kc*8 + q*2 + 1];
    short8 afr;
    afr[0] = (short)f2bf(xa.x); afr[1] = (short)f2bf(xa.y);
    afr[2] = (short)f2bf(xa.z); afr[3] = (short)f2bf(xa.w);
    afr[4] = (short)f2bf(xb.x); afr[5] = (short)f2bf(xb.y);
    afr[6] = (short)f2bf(xb.z); afr[7] = (short)f2bf(xb.w);
    #pragma unroll
    for (int ti = 0; ti < 8; ++ti) {
      short8 bfr = *(const short8*)(&Wt[(ti*16 + mrow)*136 + kc*32 + q*8]);
      acc[ti] = __builtin_amdgcn_mfma_f32_16x16x32_bf16(afr, bfr, acc[ti], 0, 0, 0);
    }
  }
  __syncthreads();   // all waves done reading Wt; reuse as hs
  float* hs = ((float*)Wt) + w*2112;   // 16 rows x 132 per wave
  #pragma unroll
  for (int ti = 0; ti < 8; ++ti) {
    #pragma unroll
    for (int r = 0; r < 4; ++r)
      hs[(q*4 + r)*132 + ti*16 + mrow] = acc[ti][r];   // row=q*4+r, col=16*ti+(l&15)
  }
  // epilogue: lane handles node nd=l>>2, head=l&3 (32 contiguous channels)
  {
    int nd = l >> 2, head = l & 3;
    int ndg = n0 + nd;
    const float4* hr  = (const float4*)(hs + nd*132 + head*32);
    const float4* asv = (const float4*)(atts1 + head*32);
    const float4* adv = (const float4*)(attd1 + head*32);
    float ps = 0.f, pd = 0.f;
    int pk[8];
    #pragma unroll
    for (int j = 0; j < 8; ++j) {
      float4 v = hr[j];
      float4 sa = asv[j], da = adv[j];
      ps += v.x*sa.x + v.y*sa.y + v.z*sa.z + v.w*sa.w;
      pd += v.x*da.x + v.y*da.y + v.z*da.z + v.w*da.w;
      int p = __builtin_amdgcn_cvt_pk_fp8_f32(v.x, v.y, 0, false);
      p = __builtin_amdgcn_cvt_pk_fp8_f32(v.z, v.w, p, true);
      pk[j] = p;
    }
    if (ndg < N) {
      int4* dst = (int4*)(h1f8 + (size_t)ndg*32 + head*8);
      dst[0] = make_int4(pk[0], pk[1], pk[2], pk[3]);
      dst[1] = make_int4(pk[4], pk[5], pk[6], pk[7]);
      a_s[ndg*4 + head] = ps;
      a_d[ndg*4 + head] = pd;
    }
  }
}

// -------- CSR build, XCD-sharded (shard = blockIdx & 7 heuristic) --------
__global__ __launch_bounds__(256) void k_hist_sh(const int* __restrict__ ei, int E, int Etot,
                                                 int N, int* __restrict__ deg_s) {
  int e = blockIdx.x*256 + threadIdx.x;
  if (e >= Etot) return;
  int s = blockIdx.x & 7;
  int dst = (e < E) ? ei[E + e] : (e - E);
  atomicAdd(&deg_s[s*N + dst], 1);
}

// vectorized scan: 1024 thr, 4 ints/thread -> 4096 elems/block; exclusive out
__global__ __launch_bounds__(1024) void k_scan1v(const int* __restrict__ vin,
    int* __restrict__ vout, int* __restrict__ bsums, int M) {
  __shared__ int wsum[16];
  int t = threadIdx.x;
  int lane = t & 63, wave = t >> 6;
  size_t base = (size_t)blockIdx.x*4096 + (size_t)t*4;
  int4 v = make_int4(0,0,0,0);
  if (base + 3 < (size_t)M) {
    v = *(const int4*)(vin + base);
  } else {
    if (base+0 < (size_t)M) v.x = vin[base+0];
    if (base+1 < (size_t)M) v.y = vin[base+1];
    if (base+2 < (size_t)M) v.z = vin[base+2];
    if (base+3 < (size_t)M) v.w = vin[base+3];
  }
  int s0 = v.x, s1 = s0 + v.y, s2 = s1 + v.z, tot = s2 + v.w;
  int inc = tot;
  #pragma unroll
  for (int off = 1; off < 64; off <<= 1) {
    int u = __shfl_up(inc, off, 64);
    if (lane >= off) inc += u;
  }
  if (lane == 63) wsum[wave] = inc;
  __syncthreads();
  if (t < 16) {
    int w = wsum[t];
    int iw = w;
    #pragma unroll
    for (int off = 1; off < 16; off <<= 1) {
      int u = __shfl_up(iw, off, 16);
      if (t >= off) iw += u;
    }
    wsum[t] = iw - w;
    if (t == 15) bsums[blockIdx.x] = iw;
  }
  __syncthreads();
  int offb = wsum[wave] + (inc - tot);
  int4 o = make_int4(offb, offb + s0, offb + s1, offb + s2);
  if (base + 3 < (size_t)M) {
    *(int4*)(vout + base) = o;
  } else {
    if (base+0 < (size_t)M) vout[base+0] = o.x;
    if (base+1 < (size_t)M) vout[base+1] = o.y;
    if (base+2 < (size_t)M) vout[base+2] = o.z;
    if (base+3 < (size_t)M) vout[base+3] = o.w;
  }
}

// scan3A with INLINE scan of bsums (nb <= 256): SP += offset, cursor = SP, SP[M]=total
__global__ __launch_bounds__(256) void k_scan3A(int* __restrict__ SP,
    int* __restrict__ cursor, const int* __restrict__ bsums, int nb, int M, int total) {
  __shared__ int sc[256];
  int t = threadIdx.x;
  sc[t] = (t < nb) ? bsums[t] : 0;
  __syncthreads();
  for (int off = 1; off < 256; off <<= 1) {
    int v = (t >= off) ? sc[t - off] : 0;
    __syncthreads();
    sc[t] += v;
    __syncthreads();
  }
  int i = blockIdx.x*256 + t;
  if (i < M) {
    int blk = i >> 12;
    int add = (blk == 0) ? 0 : sc[blk - 1];
    int r = SP[i] + add;
    SP[i] = r;
    cursor[i] = r;
  }
  if (i == 0) SP[M] = total;
}

__global__ __launch_bounds__(256) void k_scatter_sh(const int* __restrict__ ei, int E, int Etot,
    int N, int* __restrict__ cursor, int* __restrict__ srcs_sh) {
  int e = blockIdx.x*256 + threadIdx.x;
  if (e >= Etot) return;
  int s = blockIdx.x & 7;
  int src, dst;
  if (e < E) { src = ei[e]; dst = ei[E + e]; } else { src = e - E; dst = src; }
  int pos = atomicAdd(&cursor[s*N + dst], 1);
  srcs_sh[pos] = src;
}

// compact: pure shard-major -> dst-major copy + rowptr (8 lanes per dst)
__global__ __launch_bounds__(256) void k_compact(const int* __restrict__ SP,
    const int* __restrict__ srcs_sh, int* __restrict__ srcs,
    int* __restrict__ rowptr, int N, int Etot) {
  int tid = blockIdx.x*256 + threadIdx.x;
  if (tid == 0) rowptr[N] = Etot;
  int dst = tid >> 3;
  if (dst >= N) return;
  int s = tid & 7;
  int shbase = SP[s*N];
  int bg = SP[s*N + dst];
  int cnt = SP[s*N + dst + 1] - bg;
  int t_s = bg - shbase;
  int rsum = t_s;
  rsum += __shfl_xor(rsum, 1, 8);
  rsum += __shfl_xor(rsum, 2, 8);
  rsum += __shfl_xor(rsum, 4, 8);
  int incl = cnt;
  #pragma unroll
  for (int d = 1; d < 8; d <<= 1) {
    int o = __shfl_up(incl, d, 8);
    if (s >= d) incl += o;
  }
  int base = rsum + (incl - cnt);
  if (s == 0) rowptr[dst] = rsum;
  for (int k = 0; k < cnt; ++k) srcs[base + k] = srcs_sh[bg + k];
}

// -------- layer-1 aggregation (fp8 gather, lane-split exp) + fused GEMM2 --------
__global__ __launch_bounds__(256) void k_agg1g2(const int* __restrict__ rowptr,
    const int* __restrict__ srcs, const float* __restrict__ a_s,
    const float* __restrict__ a_d, const int* __restrict__ h1f8,
    const float* __restrict__ b1, const float* __restrict__ W2,
    const float* __restrict__ atts2, const float* __restrict__ attd2,
    unsigned short* __restrict__ gb, float* __restrict__ a_s2, float* __restrict__ a_d2,
    int N) {
  __shared__ float W2t[1280];   // W2t[c*128 + k] = W2[k*10 + c]
  __shared__ float att2s[20];
  int t = threadIdx.x;
  for (int f = t; f < 1280; f += 256) {
    int c = f >> 7, k = f & 127;
    W2t[f] = W2[k*10 + c];
  }
  if (t < 20) att2s[t] = (t < 10) ? atts2[t] : attd2[t - 10];
  __syncthreads();

  int dst = (blockIdx.x*256 + t) >> 5;
  if (dst >= N) return;
  int l = t & 31;
  int head = l >> 3;
  int eh = l & 3;
  int ee = l >> 2;
  int beg = rowptr[dst], end = rowptr[dst+1];
  float4 ad4 = ((const float4*)a_d)[dst];
  float adh = (eh==0) ? ad4.x : (eh==1) ? ad4.y : (eh==2) ? ad4.z : ad4.w;
  float denom = 0.f;
  float4 acc = make_float4(0.f, 0.f, 0.f, 0.f);
  for (int j = beg; j < end; j += 8) {
    int rm = end - j - 1;
    int je = j + (ee < rm ? ee : rm);
    int se = srcs[je];
    float4 as4 = ((const float4*)a_s)[se];
    float ash = (eh==0) ? as4.x : (eh==1) ? as4.y : (eh==2) ? as4.z : as4.w;
    float w = __expf(LRELU(ash + adh));
    if (ee > rm) w = 0.f;
    #pragma unroll
    for (int e = 0; e < 8; ++e) {
      int s_e   = __shfl(se, e*4, 32);
      float w_e = __shfl(w, e*4 + head, 32);
      int u = h1f8[(size_t)s_e*32 + l];
      v2f lo = __builtin_amdgcn_cvt_pk_f32_fp8(u, false);
      v2f hi = __builtin_amdgcn_cvt_pk_f32_fp8(u, true);
      acc.x += w_e*lo.x; acc.y += w_e*lo.y;
      acc.z += w_e*hi.x; acc.w += w_e*hi.y;
      denom += w_e;
    }
  }
  float inv = 1.0f / (denom + 1e-16f);
  float4 b14 = ((const float4*)b1)[l];
  float h0 = acc.x*inv + b14.x; h0 = h0 > 0.f ? h0 : __expf(h0) - 1.0f;
  float h1v = acc.y*inv + b14.y; h1v = h1v > 0.f ? h1v : __expf(h1v) - 1.0f;
  float h2v = acc.z*inv + b14.z; h2v = h2v > 0.f ? h2v : __expf(h2v) - 1.0f;
  float h3v = acc.w*inv + b14.w; h3v = h3v > 0.f ? h3v : __expf(h3v) - 1.0f;
  const float4* W2t4 = (const float4*)W2t;
  float p[10];
  #pragma unroll
  for (int c = 0; c < 10; ++c) {
    float4 wv = W2t4[c*32 + l];
    p[c] = h0*wv.x + h1v*wv.y + h2v*wv.z + h3v*wv.w;
  }
  #pragma unroll
  for (int off = 16; off > 0; off >>= 1) {
    #pragma unroll
    for (int c = 0; c < 10; ++c)
      p[c] += __shfl_xor(p[c], off, 32);
  }
  if (l < 10) {
    float val = p[0];
    #pragma unroll
    for (int c = 1; c < 10; ++c) val = (l == c) ? p[c] : val;
    gb[(size_t)dst*16 + l] = f2bf(val);   // bf16, 32B-padded rows
  }
  if (l == 0) {
    float as = 0.f, adv = 0.f;
    #pragma unroll
    for (int c = 0; c < 10; ++c) {
      as  += p[c]*att2s[c];
      adv += p[c]*att2s[10 + c];
    }
    a_s2[dst] = as;
    a_d2[dst] = adv;
  }
}

// -------- layer-2 aggregation, edges-across-lanes, bf16 g, fused pool --------
__global__ __launch_bounds__(256) void k_agg2f(const int* __restrict__ rowptr,
    const int* __restrict__ srcs, const float* __restrict__ a_s,
    const float* __restrict__ a_d, const unsigned short* __restrict__ gb,
    const float* __restrict__ b2, const int* __restrict__ batch,
    float* __restrict__ pooled, float* __restrict__ cnt, int N) {
  __shared__ float lp[4*10];
  __shared__ float lc[4];
  __shared__ int b0s;
  int t = threadIdx.x;
  int dst = (blockIdx.x*256 + t) >> 4;
  int l = t & 15;
  if (t < 40) lp[t] = 0.f;
  if (t < 4) lc[t] = 0.f;
  if (t == 0) {
    int d0 = (blockIdx.x*256) >> 4;
    if (d0 > N - 1) d0 = N - 1;
    b0s = batch[d0];
  }
  __syncthreads();
  int b0 = b0s;
  bool valid = (dst < N);
  float o = 0.f;
  int b = 0;
  if (valid) {
    int beg = rowptr[dst], end = rowptr[dst+1];
    float ad = a_d[dst];
    float acc[10] = {};
    float denom = 0.f;
    const uint4* g4 = (const uint4*)gb;
    const unsigned* gu = (const unsigned*)gb;
    for (int j = beg + l; j < end; j += 16) {
      int s = srcs[j];
      float w = __expf(LRELU(a_s[s] + ad));
      uint4 A = g4[(size_t)s*2];
      unsigned B = gu[(size_t)s*8 + 4];
      denom += w;
      acc[0] += w*bflo(A.x); acc[1] += w*bfhi(A.x);
      acc[2] += w*bflo(A.y); acc[3] += w*bfhi(A.y);
      acc[4] += w*bflo(A.z); acc[5] += w*bfhi(A.z);
      acc[6] += w*bflo(A.w); acc[7] += w*bfhi(A.w);
      acc[8] += w*bflo(B);   acc[9] += w*bfhi(B);
    }
    #pragma unroll
    for (int off = 8; off > 0; off >>= 1) {
      denom += __shfl_xor(denom, off, 16);
      #pragma unroll
      for (int c = 0; c < 10; ++c) acc[c] += __shfl_xor(acc[c], off, 16);
    }
    b = batch[dst];
    if (l < 10) {
      o = acc[l] / (denom + 1e-16f) + b2[l];
      o = o > 0.f ? o : __expf(o) - 1.0f;
    }
  }
  if (valid) {
    int bl = b - b0;
    if (l < 10) {
      if (bl < 4) atomicAdd(&lp[bl*10 + l], o);
      else atomicAdd(&pooled[b*10 + l], o);
    }
    if (l == 0) {
      if (bl < 4) atomicAdd(&lc[bl], 1.0f);
      else atomicAdd(&cnt[b], 1.0f);
    }
  }
  __syncthreads();
  if (t < 40) {
    int bl = t / 10, c = t - bl*10;
    int bb = b0 + bl;
    if (bb < 128 && lp[t] != 0.f) atomicAdd(&pooled[bb*10 + c], lp[t]);
  }
  if (t < 4) {
    int bb = b0 + t;
    if (bb < 128 && lc[t] != 0.f) atomicAdd(&cnt[bb], lc[t]);
  }
}

__global__ __launch_bounds__(128) void k_softmax(const float* __restrict__ pooled,
    const float* __restrict__ cnt, float* __restrict__ out) {
  int t = threadIdx.x;
  float inv = 1.0f / fmaxf(cnt[t], 1.0f);
  float v[10], m = -1e30f;
  #pragma unroll
  for (int c = 0; c < 10; ++c) { v[c] = pooled[t*10 + c] * inv; m = fmaxf(m, v[c]); }
  float s = 0.f;
  #pragma unroll
  for (int c = 0; c < 10; ++c) s += __expf(v[c] - m);
  float ls = logf(s) + m;
  #pragma unroll
  for (int c = 0; c < 10; ++c) out[t*10 + c] = v[c] - ls;
}

extern "C" void kernel_launch(void* const* d_in, const int* in_sizes, int n_in,
                              void* d_out, int out_size, void* d_ws, size_t ws_size,
                              hipStream_t stream) {
  const float* x     = (const float*)d_in[0];
  const float* W1    = (const float*)d_in[1];
  const float* atts1 = (const float*)d_in[2];
  const float* attd1 = (const float*)d_in[3];
  const float* b1    = (const float*)d_in[4];
  const float* W2    = (const float*)d_in[5];
  const float* atts2 = (const float*)d_in[6];
  const float* attd2 = (const float*)d_in[7];
  const float* b2    = (const float*)d_in[8];
  const int*   ei    = (const int*)d_in[9];
  const int*   batch = (const int*)d_in[10];
  int N = in_sizes[10];
  int E = in_sizes[9] / 2;
  int Etot = E + N;
  int M8 = 8 * N;

  char* base = (char*)d_ws;
  size_t off = 0;
  auto allocB = [&](size_t bytes) { void* p = (void*)(base + off); off += (bytes + 63) & ~size_t(63); return p; };

  int*   h1f8   = (int*)allocB((size_t)N*32*sizeof(int));
  float* a_s1   = (float*)allocB((size_t)N*4*sizeof(float));
  float* a_d1   = (float*)allocB((size_t)N*4*sizeof(float));
  unsigned short* gb = (unsigned short*)allocB((size_t)N*16*sizeof(unsigned short));
  float* a_s2   = (float*)allocB((size_t)N*sizeof(float));
  float* a_d2   = (float*)allocB((size_t)N*sizeof(float));
  float* poolcnt= (float*)allocB(1408*sizeof(float));   // pooled[1280] + cnt[128]
  int* deg_s  = (int*)allocB((size_t)M8*sizeof(int));
  int* SP     = (int*)allocB((size_t)(M8+1)*sizeof(int));
  int* cursor = (int*)allocB((size_t)M8*sizeof(int));
  int* rowptr = (int*)allocB((size_t)(N+1)*sizeof(int));
  int* bsumsA = (int*)allocB(1024*sizeof(int));
  int* srcs_sh= (int*)allocB((size_t)Etot*sizeof(int));
  int* srcs   = (int*)allocB((size_t)Etot*sizeof(int));

  float* pooled = poolcnt;
  float* cnt    = poolcnt + 1280;
  int nbA = (M8 + 4095) / 4096;   // 196 for N=100k (<=256 required by k_scan3A)

  k_gemm1<<<dim3((N + 63)/64), dim3(256), 0, stream>>>(x, W1, atts1, attd1, h1f8,
                                                       a_s1, a_d1, deg_s, M8, poolcnt, N);
  k_hist_sh<<<dim3((Etot + 255)/256), dim3(256), 0, stream>>>(ei, E, Etot, N, deg_s);
  k_scan1v<<<dim3(nbA), dim3(1024), 0, stream>>>(deg_s, SP, bsumsA, M8);
  k_scan3A<<<dim3((M8 + 255)/256), dim3(256), 0, stream>>>(SP, cursor, bsumsA, nbA, M8, Etot);
  k_scatter_sh<<<dim3((Etot + 255)/256), dim3(256), 0, stream>>>(ei, E, Etot, N, cursor, srcs_sh);
  k_compact<<<dim3((N*8 + 255)/256), dim3(256), 0, stream>>>(SP, srcs_sh, srcs, rowptr, N, Etot);
  k_agg1g2<<<dim3((N*32 + 255)/256), dim3(256), 0, stream>>>(rowptr, srcs, a_s1, a_d1, h1f8,
                                                             b1, W2, atts2, attd2,
                                                             gb, a_s2, a_d2, N);
  k_agg2f<<<dim3((N*16 + 255)/256), dim3(256), 0, stream>>>(rowptr, srcs, a_s2, a_d2, gb,
                                                            b2, batch, pooled, cnt, N);
  k_softmax<<<dim3(1), dim3(128), 0, stream>>>(pooled, cnt, (float*)d_out);
}